// Round 4
// baseline (781.707 us; speedup 1.0000x reference)
//
#include <hip/hip_runtime.h>
#include <math.h>

// FNO: N=16, H=64, NT=128, NX=128, M=12, DH=128, DIN=128
// h kept in two forms: f32 [b][c][t][x]  and split-bf16 transposed hT[b,t][x][c] (hi/lo planes).
// All weights/tables pre-split to bf16 hi/lo once per launch.
// conv/head/dftx are zero-LDS MFMA kernels (split-bf16, 3 pairings: hh + hl + lh).

typedef __attribute__((ext_vector_type(8))) short short8;
typedef __attribute__((ext_vector_type(4))) float f32x4;

__device__ inline unsigned short bf16rn(float v) {
    unsigned int b = __float_as_uint(v);
    return (unsigned short)((b + 0x7FFFu + ((b >> 16) & 1u)) >> 16);
}
__device__ inline void split2(float v, unsigned short& h, unsigned short& l) {
    h = bf16rn(v);
    float hf = __uint_as_float((unsigned int)h << 16);
    l = bf16rn(v - hf);
}
__device__ inline short8 ld8(const unsigned short* p) {
    return *reinterpret_cast<const short8*>(p);
}
__device__ inline float gelu_erf(float v) {
    return 0.5f * v * (1.0f + erff(v * 0.70710678118654752f));
}

// ---------------- tables ----------------
// Tf_t/Ti_t: f32 [24][128] float2 (forward/inverse t-twiddles) for fp32 dftt/idftt.
// TfH/TfL: [32][128] bf16 planes; row 2kx = cos, 2kx+1 = -sin (forward x-DFT, rows 24-31 zero).
// TiXH/TiXL: [128][32]; col 2kx = w*cos, 2kx+1 = -w*sin, w=(kx?2:1)/16384 (cols 24-31 zero).
__global__ __launch_bounds__(256) void k_tables(float* Tf_t, float* Ti_t,
                                                unsigned short* TfH, unsigned short* TfL,
                                                unsigned short* TiXH, unsigned short* TiXL) {
    int tid = threadIdx.x;
    const float STEP = 6.2831853071795864769f / 128.0f;
    for (int i = tid; i < 24 * 128; i += 256) {
        int kti = i >> 7, t = i & 127;
        int f = (kti < 12) ? kti : (kti + 104);
        int r = (f * t) & 127;
        float th = r * STEP;
        float c = cosf(th), s = sinf(th);
        Tf_t[2 * i] = c; Tf_t[2 * i + 1] = -s;
        Ti_t[2 * i] = c; Ti_t[2 * i + 1] = s;
    }
    for (int i = tid; i < 32 * 128; i += 256) {
        int row = i >> 7, x = i & 127;
        float v = 0.f;
        if (row < 24) {
            int kx = row >> 1;
            int r = (kx * x) & 127;
            float th = r * STEP;
            v = (row & 1) ? -sinf(th) : cosf(th);
        }
        unsigned short h, l; split2(v, h, l);
        TfH[i] = h; TfL[i] = l;
    }
    for (int i = tid; i < 128 * 32; i += 256) {
        int x = i >> 5, col = i & 31;
        float v = 0.f;
        if (col < 24) {
            int kx = col >> 1;
            int r = (kx * x) & 127;
            float th = r * STEP;
            float w = (kx == 0 ? 1.0f : 2.0f) / 16384.0f;
            v = (col & 1) ? -w * sinf(th) : w * cosf(th);
        }
        unsigned short h, l; split2(v, h, l);
        TiXH[i] = h; TiXL[i] = l;
    }
}

// pre-split wconv [4][64][64] and fc1w [128][64]
__global__ __launch_bounds__(256) void k_wprep(const float* __restrict__ wconv, const float* __restrict__ fc1w,
                                               unsigned short* WH, unsigned short* WL,
                                               unsigned short* F1H, unsigned short* F1L) {
    int i = blockIdx.x * 256 + threadIdx.x;
    if (i < 16384) split2(wconv[i], WH[i], WL[i]);
    if (i < 8192)  split2(fc1w[i], F1H[i], F1L[i]);
}

// ---------------- fc0 ----------------
__global__ void k_u(const float* __restrict__ u0, const float* __restrict__ w,
                    const float* __restrict__ bias, float* __restrict__ U) {
    int b = blockIdx.x, c = threadIdx.x;
    float acc = bias[c];
    const float* wr = w + c * 130 + 2;
    const float* ur = u0 + b * 128;
    for (int d = 0; d < 128; ++d) acc += ur[d] * wr[d];
    U[b * 64 + c] = acc;
}

__global__ __launch_bounds__(256) void k_fc0(const float* __restrict__ xs, const float* __restrict__ ts,
                                             const float* __restrict__ w, const float* __restrict__ U,
                                             float* __restrict__ h) {
    int idx = blockIdx.x * 256 + threadIdx.x;
    int x4 = idx & 31;
    int t  = (idx >> 5) & 127;
    int c  = (idx >> 12) & 63;
    int b  = idx >> 18;
    float w0 = w[c * 130];
    float base = ts[t] * w[c * 130 + 1] + U[b * 64 + c];
    float4 xv = reinterpret_cast<const float4*>(xs)[x4];
    float4 o;
    o.x = xv.x * w0 + base; o.y = xv.y * w0 + base;
    o.z = xv.z * w0 + base; o.w = xv.w * w0 + base;
    reinterpret_cast<float4*>(h)[idx] = o;
}

// one-time h -> hT split (after fc0); conv epilogue maintains hT afterwards
__global__ __launch_bounds__(256) void k_hsplit(const float* __restrict__ h,
                                                unsigned short* __restrict__ hTH, unsigned short* __restrict__ hTL) {
    __shared__ float hs[64][68];
    int bid = blockIdx.x, tid = threadIdx.x;
    int xh = bid & 1, t = (bid >> 1) & 127, b = bid >> 8;
    const float* hb = h + ((size_t)(b * 64) * 128 + t) * 128 + xh * 64;
    for (int i4 = tid; i4 < 1024; i4 += 256) {
        int c = i4 >> 4, x4 = (i4 & 15) << 2;
        *reinterpret_cast<float4*>(&hs[c][x4]) = *reinterpret_cast<const float4*>(&hb[(size_t)c * 16384 + x4]);
    }
    __syncthreads();
    int x = tid & 63, cb = tid >> 6;
    size_t rowbase = ((size_t)(b * 128 + t) * 128 + xh * 64 + x) * 64;
#pragma unroll
    for (int rep = 0; rep < 2; ++rep) {
        int c0 = cb * 8 + rep * 32;
        unsigned short hh[8], ll[8];
#pragma unroll
        for (int j = 0; j < 8; ++j) split2(hs[c0 + j][x], hh[j], ll[j]);
        *reinterpret_cast<uint4*>(&hTH[rowbase + c0]) = make_uint4(
            (unsigned)hh[0] | ((unsigned)hh[1] << 16), (unsigned)hh[2] | ((unsigned)hh[3] << 16),
            (unsigned)hh[4] | ((unsigned)hh[5] << 16), (unsigned)hh[6] | ((unsigned)hh[7] << 16));
        *reinterpret_cast<uint4*>(&hTL[rowbase + c0]) = make_uint4(
            (unsigned)ll[0] | ((unsigned)ll[1] << 16), (unsigned)ll[2] | ((unsigned)ll[3] << 16),
            (unsigned)ll[4] | ((unsigned)ll[5] << 16), (unsigned)ll[6] | ((unsigned)ll[7] << 16));
    }
}

// ---------------- weight pre-transpose for fp32 k_mix ----------------
__global__ __launch_bounds__(256) void k_wt(const float* __restrict__ w1re, const float* __restrict__ w1im,
                                            const float* __restrict__ w2re, const float* __restrict__ w2im,
                                            float2* __restrict__ Wt) {
    __shared__ float ldsre[32 * 145];
    __shared__ float ldsim[32 * 145];
    int bid = blockIdx.x, tid = threadIdx.x;
    int c = bid & 63, tbl = (bid >> 6) & 1, l = bid >> 7;
    const float* re = (tbl ? w2re : w1re) + (size_t)((l * 64 + c) * 64) * 144;
    const float* im = (tbl ? w2im : w1im) + (size_t)((l * 64 + c) * 64) * 144;
    int moff = tbl * 144;
    for (int half = 0; half < 2; ++half) {
        __syncthreads();
        for (int i = tid; i < 32 * 144; i += 256) {
            int o = i / 144, m = i - o * 144;
            ldsre[o * 145 + m] = re[(half * 32 + o) * 144 + m];
            ldsim[o * 145 + m] = im[(half * 32 + o) * 144 + m];
        }
        __syncthreads();
        for (int i = tid; i < 32 * 144; i += 256) {
            int mode = i >> 5, o = i & 31;
            Wt[((size_t)(l * 288 + moff + mode) * 64 + c) * 64 + half * 32 + o] =
                make_float2(ldsre[o * 145 + mode], ldsim[o * 145 + mode]);
        }
    }
}

// ---------------- forward DFT over x: zero-LDS MFMA ----------------
// D[row][col] = sum_x h[row][x] * Tf[col][x]; rows = (b,c,t) flat, cols 0..23 (even=re, odd=im)
__global__ __launch_bounds__(256) void k_dftx(const float* __restrict__ h,
                                              const unsigned short* __restrict__ TfH,
                                              const unsigned short* __restrict__ TfL,
                                              float* __restrict__ Aout) {
    int blk = blockIdx.x, tid = threadIdx.x;
    int w = tid >> 6, lane = tid & 63, ln = lane & 15, lg = lane >> 4;
    f32x4 acc[2];
    acc[0] = (f32x4){0.f, 0.f, 0.f, 0.f};
    acc[1] = (f32x4){0.f, 0.f, 0.f, 0.f};
    const float* hrow = h + ((size_t)blk * 64 + w * 16 + ln) * 128;
#pragma unroll
    for (int kt = 0; kt < 4; ++kt) {
        const float* hp = hrow + kt * 32 + lg * 8;
        float4 a0 = *reinterpret_cast<const float4*>(hp);
        float4 a1 = *reinterpret_cast<const float4*>(hp + 4);
        short8 ah, al;
        unsigned short hh, ll;
        split2(a0.x, hh, ll); ah[0] = (short)hh; al[0] = (short)ll;
        split2(a0.y, hh, ll); ah[1] = (short)hh; al[1] = (short)ll;
        split2(a0.z, hh, ll); ah[2] = (short)hh; al[2] = (short)ll;
        split2(a0.w, hh, ll); ah[3] = (short)hh; al[3] = (short)ll;
        split2(a1.x, hh, ll); ah[4] = (short)hh; al[4] = (short)ll;
        split2(a1.y, hh, ll); ah[5] = (short)hh; al[5] = (short)ll;
        split2(a1.z, hh, ll); ah[6] = (short)hh; al[6] = (short)ll;
        split2(a1.w, hh, ll); ah[7] = (short)hh; al[7] = (short)ll;
#pragma unroll
        for (int nt = 0; nt < 2; ++nt) {
            int off = (nt * 16 + ln) * 128 + kt * 32 + lg * 8;
            short8 bh = ld8(TfH + off);
            short8 bl = ld8(TfL + off);
            acc[nt] = __builtin_amdgcn_mfma_f32_16x16x32_bf16(ah, bh, acc[nt], 0, 0, 0);
            acc[nt] = __builtin_amdgcn_mfma_f32_16x16x32_bf16(ah, bl, acc[nt], 0, 0, 0);
            acc[nt] = __builtin_amdgcn_mfma_f32_16x16x32_bf16(al, bh, acc[nt], 0, 0, 0);
        }
    }
    size_t obase = (size_t)blk * 64 + w * 16 + lg * 4;
#pragma unroll
    for (int nt = 0; nt < 2; ++nt) {
        int col = nt * 16 + ln;
        if (col < 24) {
#pragma unroll
            for (int r = 0; r < 4; ++r) Aout[(obase + r) * 24 + col] = acc[nt][r];
        }
    }
}

// ---------------- forward DFT over t (fp32) ----------------
__global__ __launch_bounds__(256) void k_dftt(const float2* __restrict__ A, const float* __restrict__ Tf_t,
                                              float2* __restrict__ Hm) {
    __shared__ float2 al[128 * 12];
    __shared__ float2 tt[24 * 129];
    int bc = blockIdx.x, tid = threadIdx.x;
    const float2* src = A + (size_t)bc * 128 * 12;
    for (int i = tid; i < 128 * 12; i += 256) al[i] = src[i];
    const float2* tg = (const float2*)Tf_t;
    for (int i = tid; i < 24 * 128; i += 256) {
        int kt = i >> 7, t = i & 127;
        tt[kt * 129 + t] = tg[i];
    }
    __syncthreads();
    int b = bc >> 6, c = bc & 63;
    for (int oi = tid; oi < 288; oi += 256) {
        int kt = oi / 12, kx = oi - kt * 12;
        float hr = 0.f, hi = 0.f;
        const float2* tp = tt + kt * 129;
#pragma unroll 4
        for (int t = 0; t < 128; ++t) {
            float2 a = al[t * 12 + kx];
            float2 wv = tp[t];
            hr += a.x * wv.x - a.y * wv.y;
            hi += a.x * wv.y + a.y * wv.x;
        }
        Hm[((size_t)oi * 16 + b) * 64 + c] = make_float2(hr, hi);
    }
}

// ---------------- per-mode channel mix (fp32) ----------------
__global__ __launch_bounds__(256) void k_mix(const float2* __restrict__ Hm, const float2* __restrict__ WtL,
                                             float2* __restrict__ Om) {
    __shared__ float2 hl[8 * 64];
    int bid = blockIdx.x, tid = threadIdx.x;
    int mode = bid >> 1, bh = bid & 1;
    const float2* hsrc = Hm + ((size_t)mode * 16 + bh * 8) * 64;
    for (int i = tid; i < 512; i += 256) hl[i] = hsrc[i];
    __syncthreads();
    int o = tid & 63, bg = tid >> 6;
    const float2* wp = WtL + (size_t)mode * 4096 + o;
    const float2* h0 = hl + (bg * 2) * 64;
    const float2* h1 = hl + (bg * 2 + 1) * 64;
    float a0r = 0.f, a0i = 0.f, a1r = 0.f, a1i = 0.f;
#pragma unroll 4
    for (int c = 0; c < 64; ++c) {
        float2 wv = wp[c * 64];
        float2 a0 = h0[c], a1 = h1[c];
        a0r += a0.x * wv.x - a0.y * wv.y;
        a0i += a0.x * wv.y + a0.y * wv.x;
        a1r += a1.x * wv.x - a1.y * wv.y;
        a1i += a1.x * wv.y + a1.y * wv.x;
    }
    int b0 = bh * 8 + bg * 2;
    Om[((size_t)(b0)*64 + o) * 288 + mode]       = make_float2(a0r, a0i);
    Om[((size_t)(b0 + 1) * 64 + o) * 288 + mode] = make_float2(a1r, a1i);
}

__global__ __launch_bounds__(256) void k_mix_raw(const float2* __restrict__ Hm,
                                                 const float* __restrict__ w1re, const float* __restrict__ w1im,
                                                 const float* __restrict__ w2re, const float* __restrict__ w2im,
                                                 float2* __restrict__ Om) {
    __shared__ float2 hl[8 * 64];
    int bid = blockIdx.x, tid = threadIdx.x;
    int mode = bid >> 1, bh = bid & 1;
    const float2* hsrc = Hm + ((size_t)mode * 16 + bh * 8) * 64;
    for (int i = tid; i < 512; i += 256) hl[i] = hsrc[i];
    __syncthreads();
    int kti = mode / 12, kx = mode - kti * 12;
    const float* re; const float* im; int ktw;
    if (kti < 12) { re = w1re; im = w1im; ktw = kti; }
    else          { re = w2re; im = w2im; ktw = kti - 12; }
    int off = ktw * 12 + kx;
    int o = tid & 63, bg = tid >> 6;
    const float2* h0 = hl + (bg * 2) * 64;
    const float2* h1 = hl + (bg * 2 + 1) * 64;
    float a0r = 0.f, a0i = 0.f, a1r = 0.f, a1i = 0.f;
    for (int c = 0; c < 64; ++c) {
        size_t widx = (size_t)(c * 64 + o) * 144 + off;
        float wr = re[widx], wi = im[widx];
        float2 a0 = h0[c], a1 = h1[c];
        a0r += a0.x * wr - a0.y * wi;
        a0i += a0.x * wi + a0.y * wr;
        a1r += a1.x * wr - a1.y * wi;
        a1i += a1.x * wi + a1.y * wr;
    }
    int b0 = bh * 8 + bg * 2;
    Om[((size_t)(b0)*64 + o) * 288 + mode]       = make_float2(a0r, a0i);
    Om[((size_t)(b0 + 1) * 64 + o) * 288 + mode] = make_float2(a1r, a1i);
}

// ---------------- inverse DFT over t (fp32 math, split-bf16 output) ----------------
// BvH/BvL layout: [(b*64+o)*128 + t][32] shorts; cols 2kx=re, 2kx+1=im, 24..31 zero
__global__ __launch_bounds__(256) void k_idftt(const float2* __restrict__ Om, const float* __restrict__ Ti_t,
                                               unsigned short* __restrict__ BvH, unsigned short* __restrict__ BvL) {
    __shared__ float2 ol[288];
    __shared__ float2 tt[24 * 129];
    int bo = blockIdx.x, tid = threadIdx.x;
    const float2* src = Om + (size_t)bo * 288;
    for (int i = tid; i < 288; i += 256) ol[i] = src[i];
    const float2* tg = (const float2*)Ti_t;
    for (int i = tid; i < 24 * 128; i += 256) {
        int kt = i >> 7, t = i & 127;
        tt[kt * 129 + t] = tg[i];
    }
    __syncthreads();
    size_t obase = (size_t)bo * 128 * 32;
#pragma unroll
    for (int k = 0; k < 6; ++k) {
        int oi = tid + k * 256;
        int t = oi / 12, kx = oi - t * 12;
        float br = 0.f, bi = 0.f;
#pragma unroll
        for (int kt = 0; kt < 24; ++kt) {
            float2 a = ol[kt * 12 + kx];
            float2 wv = tt[kt * 129 + t];
            br += a.x * wv.x - a.y * wv.y;
            bi += a.x * wv.y + a.y * wv.x;
        }
        unsigned short h1, l1, h2, l2;
        split2(br, h1, l1); split2(bi, h2, l2);
        size_t p = obase + (size_t)t * 32 + 2 * kx;
        BvH[p] = h1; BvH[p + 1] = h2;
        BvL[p] = l1; BvL[p + 1] = l2;
    }
    if (tid < 128) {
        size_t p = obase + (size_t)tid * 32 + 24;
        *reinterpret_cast<uint4*>(&BvH[p]) = make_uint4(0, 0, 0, 0);
        *reinterpret_cast<uint4*>(&BvL[p]) = make_uint4(0, 0, 0, 0);
    }
}

// ---------------- conv + idft-x: zero-LDS MFMA ----------------
// block=(b,t,xh): D[o=64][x=64] = sum_{k<64} W[o][k] hT[x][k]  +  sum_{kk<24} Bv[o][kk] TiX[x][kk]
// DOGELU: gelu + write h f32; always updates hT (after barrier).
template <int DOGELU>
__global__ __launch_bounds__(256) void k_conv2(float* __restrict__ h,
                                               unsigned short* __restrict__ hTH, unsigned short* __restrict__ hTL,
                                               const unsigned short* __restrict__ WH, const unsigned short* __restrict__ WL,
                                               const unsigned short* __restrict__ BvH, const unsigned short* __restrict__ BvL,
                                               const unsigned short* __restrict__ TiXH, const unsigned short* __restrict__ TiXL,
                                               const float* __restrict__ bconv) {
    int bid = blockIdx.x, tid = threadIdx.x;
    int xh = bid & 1, t = (bid >> 1) & 127, b = bid >> 8;
    int w = tid >> 6, lane = tid & 63, ln = lane & 15, lg = lane >> 4;
    f32x4 acc[4];
#pragma unroll
    for (int nx = 0; nx < 4; ++nx) acc[nx] = (f32x4){0.f, 0.f, 0.f, 0.f};

    size_t btbase = ((size_t)(b * 128 + t) * 128 + xh * 64) * 64;
#pragma unroll
    for (int kt = 0; kt < 2; ++kt) {
        int aoff = (w * 16 + ln) * 64 + kt * 32 + lg * 8;
        short8 aH = ld8(WH + aoff);
        short8 aL = ld8(WL + aoff);
#pragma unroll
        for (int nx = 0; nx < 4; ++nx) {
            size_t boff = btbase + (size_t)(nx * 16 + ln) * 64 + kt * 32 + lg * 8;
            short8 bH = ld8(hTH + boff);
            short8 bL = ld8(hTL + boff);
            acc[nx] = __builtin_amdgcn_mfma_f32_16x16x32_bf16(aH, bH, acc[nx], 0, 0, 0);
            acc[nx] = __builtin_amdgcn_mfma_f32_16x16x32_bf16(aH, bL, acc[nx], 0, 0, 0);
            acc[nx] = __builtin_amdgcn_mfma_f32_16x16x32_bf16(aL, bH, acc[nx], 0, 0, 0);
        }
    }
    {
        size_t aoff = ((size_t)(b * 64 + w * 16 + ln) * 128 + t) * 32 + lg * 8;
        short8 aH = ld8(BvH + aoff);
        short8 aL = ld8(BvL + aoff);
#pragma unroll
        for (int nx = 0; nx < 4; ++nx) {
            int boff = (xh * 64 + nx * 16 + ln) * 32 + lg * 8;
            short8 bH = ld8(TiXH + boff);
            short8 bL = ld8(TiXL + boff);
            acc[nx] = __builtin_amdgcn_mfma_f32_16x16x32_bf16(aH, bH, acc[nx], 0, 0, 0);
            acc[nx] = __builtin_amdgcn_mfma_f32_16x16x32_bf16(aH, bL, acc[nx], 0, 0, 0);
            acc[nx] = __builtin_amdgcn_mfma_f32_16x16x32_bf16(aL, bH, acc[nx], 0, 0, 0);
        }
    }
    __syncthreads();   // all hT reads done before in-place hT writes

    float* hb = h + ((size_t)(b * 64) * 128 + t) * 128 + xh * 64;
    int o0 = w * 16 + lg * 4;
    float bc0 = bconv[o0], bc1 = bconv[o0 + 1], bc2 = bconv[o0 + 2], bc3 = bconv[o0 + 3];
#pragma unroll
    for (int nx = 0; nx < 4; ++nx) {
        int x = nx * 16 + ln;
        float v0 = acc[nx][0] + bc0;
        float v1 = acc[nx][1] + bc1;
        float v2 = acc[nx][2] + bc2;
        float v3 = acc[nx][3] + bc3;
        if (DOGELU) {
            v0 = gelu_erf(v0); v1 = gelu_erf(v1); v2 = gelu_erf(v2); v3 = gelu_erf(v3);
            hb[(size_t)(o0 + 0) * 16384 + x] = v0;
            hb[(size_t)(o0 + 1) * 16384 + x] = v1;
            hb[(size_t)(o0 + 2) * 16384 + x] = v2;
            hb[(size_t)(o0 + 3) * 16384 + x] = v3;
        }
        unsigned short hh[4], ll[4];
        split2(v0, hh[0], ll[0]); split2(v1, hh[1], ll[1]);
        split2(v2, hh[2], ll[2]); split2(v3, hh[3], ll[3]);
        size_t trow = btbase + (size_t)x * 64 + o0;
        *reinterpret_cast<uint2*>(&hTH[trow]) =
            make_uint2((unsigned)hh[0] | ((unsigned)hh[1] << 16), (unsigned)hh[2] | ((unsigned)hh[3] << 16));
        *reinterpret_cast<uint2*>(&hTL[trow]) =
            make_uint2((unsigned)ll[0] | ((unsigned)ll[1] << 16), (unsigned)ll[2] | ((unsigned)ll[3] << 16));
    }
}

// ---------------- head: fc1 + gelu + fc2, zero-LDS MFMA + small reduction ----------------
__global__ __launch_bounds__(256) void k_head2(const unsigned short* __restrict__ hTH, const unsigned short* __restrict__ hTL,
                                               const unsigned short* __restrict__ F1H, const unsigned short* __restrict__ F1L,
                                               const float* __restrict__ b1, const float* __restrict__ w2,
                                               const float* __restrict__ b2, float* __restrict__ out) {
    __shared__ float red[16][66];
    int bid = blockIdx.x, tid = threadIdx.x;
    int xh = bid & 1, t = (bid >> 1) & 127, b = bid >> 8;
    int w = tid >> 6, lane = tid & 63, ln = lane & 15, lg = lane >> 4;
    f32x4 acc[2][4];
#pragma unroll
    for (int s = 0; s < 2; ++s)
#pragma unroll
        for (int nx = 0; nx < 4; ++nx) acc[s][nx] = (f32x4){0.f, 0.f, 0.f, 0.f};

    size_t btbase = ((size_t)(b * 128 + t) * 128 + xh * 64) * 64;
#pragma unroll
    for (int kt = 0; kt < 2; ++kt) {
        short8 bH[4], bL[4];
#pragma unroll
        for (int nx = 0; nx < 4; ++nx) {
            size_t boff = btbase + (size_t)(nx * 16 + ln) * 64 + kt * 32 + lg * 8;
            bH[nx] = ld8(hTH + boff);
            bL[nx] = ld8(hTL + boff);
        }
#pragma unroll
        for (int s = 0; s < 2; ++s) {
            int aoff = ((w * 2 + s) * 16 + ln) * 64 + kt * 32 + lg * 8;
            short8 aH = ld8(F1H + aoff);
            short8 aL = ld8(F1L + aoff);
#pragma unroll
            for (int nx = 0; nx < 4; ++nx) {
                acc[s][nx] = __builtin_amdgcn_mfma_f32_16x16x32_bf16(aH, bH[nx], acc[s][nx], 0, 0, 0);
                acc[s][nx] = __builtin_amdgcn_mfma_f32_16x16x32_bf16(aH, bL[nx], acc[s][nx], 0, 0, 0);
                acc[s][nx] = __builtin_amdgcn_mfma_f32_16x16x32_bf16(aL, bH[nx], acc[s][nx], 0, 0, 0);
            }
        }
    }
    float p[4] = {0.f, 0.f, 0.f, 0.f};
#pragma unroll
    for (int s = 0; s < 2; ++s)
#pragma unroll
        for (int r = 0; r < 4; ++r) {
            int d = (w * 2 + s) * 16 + lg * 4 + r;
            float bb = b1[d], wk = w2[d];
#pragma unroll
            for (int nx = 0; nx < 4; ++nx) {
                float v = acc[s][nx][r] + bb;
                p[nx] += gelu_erf(v) * wk;
            }
        }
#pragma unroll
    for (int nx = 0; nx < 4; ++nx) red[w * 4 + lg][nx * 16 + ln] = p[nx];
    __syncthreads();
    if (tid < 64) {
        float s = 0.f;
#pragma unroll
        for (int g = 0; g < 16; ++g) s += red[g][tid];
        out[((size_t)b * 128 + t) * 128 + xh * 64 + tid] = s + b2[0];
    }
}

extern "C" void kernel_launch(void* const* d_in, const int* in_sizes, int n_in,
                              void* d_out, int out_size, void* d_ws, size_t ws_size,
                              hipStream_t stream) {
    const float* ts    = (const float*)d_in[0];
    const float* xs    = (const float*)d_in[1];
    const float* u0    = (const float*)d_in[2];
    const float* fc0_w = (const float*)d_in[3];
    const float* fc0_b = (const float*)d_in[4];
    const float* w1re  = (const float*)d_in[5];
    const float* w1im  = (const float*)d_in[6];
    const float* w2re  = (const float*)d_in[7];
    const float* w2im  = (const float*)d_in[8];
    const float* wconv = (const float*)d_in[9];
    const float* bconv = (const float*)d_in[10];
    const float* fc1w  = (const float*)d_in[11];
    const float* fc1b  = (const float*)d_in[12];
    const float* fc2w  = (const float*)d_in[13];
    const float* fc2b  = (const float*)d_in[14];
    float* out = (float*)d_out;

    char* ws = (char*)d_ws;
    size_t off = 0;
    auto alloc = [&](size_t bytes) -> char* {
        char* p = ws + off;
        off = (off + bytes + 255) & ~(size_t)255;
        return p;
    };
    float*  h    = (float*)alloc(67108864);            // [16][64][128][128] f32
    float*  A    = (float*)alloc(12582912);            // [131072][24] f32 (= [row][12] float2)
    float2* Hm   = (float2*)alloc(2359296);            // [288][16][64]
    float2* Om   = (float2*)alloc(2359296);            // [16][64][288]
    float*  U    = (float*)alloc(4096);
    float*  Tf_t = (float*)alloc(24576);
    float*  Ti_t = (float*)alloc(24576);
    unsigned short* TfH  = (unsigned short*)alloc(8192);
    unsigned short* TfL  = (unsigned short*)alloc(8192);
    unsigned short* TiXH = (unsigned short*)alloc(8192);
    unsigned short* TiXL = (unsigned short*)alloc(8192);
    unsigned short* WH   = (unsigned short*)alloc(32768);
    unsigned short* WL   = (unsigned short*)alloc(32768);
    unsigned short* F1H  = (unsigned short*)alloc(16384);
    unsigned short* F1L  = (unsigned short*)alloc(16384);
    unsigned short* BvH  = (unsigned short*)alloc(8388608);    // [1024*128][32]
    unsigned short* BvL  = (unsigned short*)alloc(8388608);
    unsigned short* hTH  = (unsigned short*)alloc(33554432);   // [16*128*128][64]
    unsigned short* hTL  = (unsigned short*)alloc(33554432);
    size_t base_need = off;
    if (ws_size < base_need) return;                   // cannot run safely
    float2* Wt = (float2*)alloc(37748736);             // [4][288][64][64]
    bool use_wt = (ws_size >= off);

    k_tables<<<1, 256, 0, stream>>>(Tf_t, Ti_t, TfH, TfL, TiXH, TiXL);
    k_wprep<<<96, 256, 0, stream>>>(wconv, fc1w, WH, WL, F1H, F1L);
    k_u<<<16, 64, 0, stream>>>(u0, fc0_w, fc0_b, U);
    k_fc0<<<16384, 256, 0, stream>>>(xs, ts, fc0_w, U, h);
    k_hsplit<<<4096, 256, 0, stream>>>(h, hTH, hTL);
    if (use_wt)
        k_wt<<<512, 256, 0, stream>>>(w1re, w1im, w2re, w2im, Wt);

    for (int l = 0; l < 4; ++l) {
        k_dftx<<<2048, 256, 0, stream>>>(h, TfH, TfL, A);
        k_dftt<<<1024, 256, 0, stream>>>((const float2*)A, Tf_t, Hm);
        if (use_wt)
            k_mix<<<576, 256, 0, stream>>>(Hm, Wt + (size_t)l * 288 * 4096, Om);
        else
            k_mix_raw<<<576, 256, 0, stream>>>(Hm, w1re + (size_t)l * 589824, w1im + (size_t)l * 589824,
                                               w2re + (size_t)l * 589824, w2im + (size_t)l * 589824, Om);
        k_idftt<<<1024, 256, 0, stream>>>(Om, Ti_t, BvH, BvL);
        if (l < 3)
            k_conv2<1><<<4096, 256, 0, stream>>>(h, hTH, hTL, WH + l * 4096, WL + l * 4096,
                                                 BvH, BvL, TiXH, TiXL, bconv + l * 64);
        else
            k_conv2<0><<<4096, 256, 0, stream>>>(h, hTH, hTL, WH + l * 4096, WL + l * 4096,
                                                 BvH, BvL, TiXH, TiXL, bconv + l * 64);
    }
    k_head2<<<4096, 256, 0, stream>>>(hTH, hTL, F1H, F1L, fc1b, fc2w, fc2b, out);
}

// Round 5
// 724.643 us; speedup vs baseline: 1.0787x; 1.0787x over previous
//
#include <hip/hip_runtime.h>
#include <math.h>

// FNO: N=16, H=64, NT=128, NX=128, M=12, DH=128, DIN=128
// R5: no f32 h. State = hT[b,t,x][c] split-bf16 (hi/lo planes).
// Layer-0 spectrum analytic (fc0 output is rank-1 separable).
// conv fuses next layer's x-DFT; t-DFT / t-iDFT are split-bf16 MFMA kernels.

typedef __attribute__((ext_vector_type(8))) short short8;
typedef __attribute__((ext_vector_type(4))) float f32x4;

__device__ inline unsigned short bf16rn(float v) {
    unsigned int b = __float_as_uint(v);
    return (unsigned short)((b + 0x7FFFu + ((b >> 16) & 1u)) >> 16);
}
__device__ inline void split2(float v, unsigned short& h, unsigned short& l) {
    h = bf16rn(v);
    float hf = __uint_as_float((unsigned int)h << 16);
    l = bf16rn(v - hf);
}
__device__ inline short8 ld8(const unsigned short* p) {
    return *reinterpret_cast<const short8*>(p);
}
__device__ inline float gelu_erf(float v) {
    return 0.5f * v * (1.0f + erff(v * 0.70710678118654752f));
}
#define MFMA3(accv, aH, aL, bH, bL) \
    accv = __builtin_amdgcn_mfma_f32_16x16x32_bf16(aH, bH, accv, 0, 0, 0); \
    accv = __builtin_amdgcn_mfma_f32_16x16x32_bf16(aH, bL, accv, 0, 0, 0); \
    accv = __builtin_amdgcn_mfma_f32_16x16x32_bf16(aL, bH, accv, 0, 0, 0);

#define STEPC 0.049087385212340519350f  // 2*pi/128

// ---------------- bf16 constant tables ----------------
// Tf  [32][128]: row 2kx=cos(2pi kx x/128), 2kx+1=-sin (fwd x-DFT A-op; rows 24-31 zero)
// TiX [128][32]: col 2kx=w*cos, 2kx+1=-w*sin, w=(kx?2:1)/16384 (inv x-DFT B-op)
// TD  [48][256]: fwd t-DFT A-op; row 2kt: [cos | sin], row 2kt+1: [-sin | cos] (k<128 | k>=128)
// TI  [128][64]: inv t-DFT A-op; col 2kt=cos, 2kt+1=-sin (cols 48-63 zero)
__global__ __launch_bounds__(256) void k_tables2(unsigned short* TfH, unsigned short* TfL,
                                                 unsigned short* TiXH, unsigned short* TiXL,
                                                 unsigned short* TDH, unsigned short* TDL,
                                                 unsigned short* TIH, unsigned short* TIL) {
    int tid = threadIdx.x;
    unsigned short h, l;
    for (int i = tid; i < 32 * 128; i += 256) {
        int row = i >> 7, x = i & 127;
        float v = 0.f;
        if (row < 24) {
            int kx = row >> 1;
            float th = ((kx * x) & 127) * STEPC;
            v = (row & 1) ? -sinf(th) : cosf(th);
        }
        split2(v, h, l); TfH[i] = h; TfL[i] = l;
    }
    for (int i = tid; i < 128 * 32; i += 256) {
        int x = i >> 5, col = i & 31;
        float v = 0.f;
        if (col < 24) {
            int kx = col >> 1;
            float th = ((kx * x) & 127) * STEPC;
            float w = (kx == 0 ? 1.0f : 2.0f) / 16384.0f;
            v = (col & 1) ? -w * sinf(th) : w * cosf(th);
        }
        split2(v, h, l); TiXH[i] = h; TiXL[i] = l;
    }
    for (int i = tid; i < 48 * 256; i += 256) {
        int row = i >> 8, k = i & 255;
        int kt = row >> 1;
        int f = (kt < 12) ? kt : (kt + 104);
        int t = k & 127;
        float th = ((f * t) & 127) * STEPC;
        float c = cosf(th), s = sinf(th);
        float v;
        if (k < 128) v = (row & 1) ? -s : c;
        else         v = (row & 1) ?  c : s;
        split2(v, h, l); TDH[i] = h; TDL[i] = l;
    }
    for (int i = tid; i < 128 * 64; i += 256) {
        int t = i >> 6, col = i & 63;
        float v = 0.f;
        if (col < 48) {
            int kt = col >> 1;
            int f = (kt < 12) ? kt : (kt + 104);
            float th = ((f * t) & 127) * STEPC;
            v = (col & 1) ? -sinf(th) : cosf(th);
        }
        split2(v, h, l); TIH[i] = h; TIL[i] = l;
    }
}

// spectral sums for analytic layer-0: Sx[kx]=sum_x xs*e^{-i th}, St[kt]=sum_t ts*e^{-i th}
__global__ void k_spec(const float* __restrict__ xs, const float* __restrict__ ts,
                       float2* __restrict__ Sx, float2* __restrict__ St) {
    int tid = threadIdx.x;
    if (tid < 12) {
        float re = 0.f, im = 0.f;
        for (int x = 0; x < 128; ++x) {
            float th = ((tid * x) & 127) * STEPC;
            re += xs[x] * cosf(th); im -= xs[x] * sinf(th);
        }
        Sx[tid] = make_float2(re, im);
    } else if (tid >= 32 && tid < 56) {
        int kt = tid - 32;
        int f = (kt < 12) ? kt : (kt + 104);
        float re = 0.f, im = 0.f;
        for (int t = 0; t < 128; ++t) {
            float th = ((f * t) & 127) * STEPC;
            re += ts[t] * cosf(th); im -= ts[t] * sinf(th);
        }
        St[kt] = make_float2(re, im);
    }
}

// pre-split wconv [4][64][64] and fc1w [128][64]
__global__ __launch_bounds__(256) void k_wprep(const float* __restrict__ wconv, const float* __restrict__ fc1w,
                                               unsigned short* WH, unsigned short* WL,
                                               unsigned short* F1H, unsigned short* F1L) {
    int i = blockIdx.x * 256 + threadIdx.x;
    if (i < 16384) split2(wconv[i], WH[i], WL[i]);
    if (i < 8192)  split2(fc1w[i], F1H[i], F1L[i]);
}

// ---------------- fc0 ----------------
__global__ void k_u(const float* __restrict__ u0, const float* __restrict__ w,
                    const float* __restrict__ bias, float* __restrict__ U) {
    int b = blockIdx.x, c = threadIdx.x;
    float acc = bias[c];
    const float* wr = w + c * 130 + 2;
    const float* ur = u0 + b * 128;
    for (int d = 0; d < 128; ++d) acc += ur[d] * wr[d];
    U[b * 64 + c] = acc;
}

// fc0 -> hT directly (split-bf16), no f32 h
__global__ __launch_bounds__(256) void k_fc0t(const float* __restrict__ xs, const float* __restrict__ ts,
                                              const float* __restrict__ fc0_w, const float* __restrict__ U,
                                              unsigned short* __restrict__ hTH, unsigned short* __restrict__ hTL) {
    __shared__ float w0c[64], basec[64];
    int bid = blockIdx.x, tid = threadIdx.x;
    int t = bid & 127, b = bid >> 7;
    if (tid < 64) {
        w0c[tid] = fc0_w[tid * 130];
        basec[tid] = ts[t] * fc0_w[tid * 130 + 1] + U[b * 64 + tid];
    }
    __syncthreads();
    int x = tid >> 1, c0 = (tid & 1) * 32;
    float xv = xs[x];
    unsigned int ph[16], pl[16];
#pragma unroll
    for (int j = 0; j < 32; j += 2) {
        unsigned short h0, l0, h1, l1;
        split2(xv * w0c[c0 + j] + basec[c0 + j], h0, l0);
        split2(xv * w0c[c0 + j + 1] + basec[c0 + j + 1], h1, l1);
        ph[j >> 1] = (unsigned)h0 | ((unsigned)h1 << 16);
        pl[j >> 1] = (unsigned)l0 | ((unsigned)l1 << 16);
    }
    size_t rb = ((size_t)((b * 128 + t) * 128 + x)) * 64 + c0;
    uint4* dh = reinterpret_cast<uint4*>(&hTH[rb]);
    uint4* dl = reinterpret_cast<uint4*>(&hTL[rb]);
#pragma unroll
    for (int q = 0; q < 4; ++q) {
        dh[q] = make_uint4(ph[4 * q], ph[4 * q + 1], ph[4 * q + 2], ph[4 * q + 3]);
        dl[q] = make_uint4(pl[4 * q], pl[4 * q + 1], pl[4 * q + 2], pl[4 * q + 3]);
    }
}

// analytic layer-0 Hm: support only on kt=0 or kx=0 axes
__global__ __launch_bounds__(256) void k_hm0(const float* __restrict__ fc0_w, const float* __restrict__ U,
                                             const float2* __restrict__ Sx, const float2* __restrict__ St,
                                             float2* __restrict__ Hm) {
    __shared__ float w0s[64], w1s[64];
    int mode = blockIdx.x, tid = threadIdx.x;
    int kt = mode / 12, kx = mode - kt * 12;
    if (tid < 64) { w0s[tid] = fc0_w[tid * 130]; w1s[tid] = fc0_w[tid * 130 + 1]; }
    __syncthreads();
    float2 sx = Sx[kx], st = St[kt];
    for (int i = tid; i < 1024; i += 256) {
        int b = i >> 6, c = i & 63;
        float re = 0.f, im = 0.f;
        if (kt == 0) { re += 128.f * w0s[c] * sx.x; im += 128.f * w0s[c] * sx.y; }
        if (kx == 0) { re += 128.f * w1s[c] * st.x; im += 128.f * w1s[c] * st.y; }
        if (kt == 0 && kx == 0) re += 16384.f * U[b * 64 + c];
        Hm[((size_t)mode * 16 + b) * 64 + c] = make_float2(re, im);
    }
}

// ---------------- weight pre-transpose for fp32 k_mix ----------------
__global__ __launch_bounds__(256) void k_wt(const float* __restrict__ w1re, const float* __restrict__ w1im,
                                            const float* __restrict__ w2re, const float* __restrict__ w2im,
                                            float2* __restrict__ Wt) {
    __shared__ float ldsre[32 * 145];
    __shared__ float ldsim[32 * 145];
    int bid = blockIdx.x, tid = threadIdx.x;
    int c = bid & 63, tbl = (bid >> 6) & 1, l = bid >> 7;
    const float* re = (tbl ? w2re : w1re) + (size_t)((l * 64 + c) * 64) * 144;
    const float* im = (tbl ? w2im : w1im) + (size_t)((l * 64 + c) * 64) * 144;
    int moff = tbl * 144;
    for (int half = 0; half < 2; ++half) {
        __syncthreads();
        for (int i = tid; i < 32 * 144; i += 256) {
            int o = i / 144, m = i - o * 144;
            ldsre[o * 145 + m] = re[(half * 32 + o) * 144 + m];
            ldsim[o * 145 + m] = im[(half * 32 + o) * 144 + m];
        }
        __syncthreads();
        for (int i = tid; i < 32 * 144; i += 256) {
            int mode = i >> 5, o = i & 31;
            Wt[((size_t)(l * 288 + moff + mode) * 64 + c) * 64 + half * 32 + o] =
                make_float2(ldsre[o * 145 + mode], ldsim[o * 145 + mode]);
        }
    }
}

// ---------------- forward t-DFT: MFMA over A2 planes ----------------
// Hm[(kt*12+kx)][b][c]: D[2kt+p][c] = sum_{k<256} TD[2kt+p][k] * A2plane[k][c]
__global__ __launch_bounds__(256) void k_dftt2(const unsigned short* __restrict__ A2H, const unsigned short* __restrict__ A2L,
                                               const unsigned short* __restrict__ TDH, const unsigned short* __restrict__ TDL,
                                               float2* __restrict__ Hm) {
    int bid = blockIdx.x, tid = threadIdx.x;
    int b = bid / 12, kx = bid - b * 12;
    int w = tid >> 6, lane = tid & 63, ln = lane & 15, lg = lane >> 4;
    f32x4 acc[3];
#pragma unroll
    for (int m = 0; m < 3; ++m) acc[m] = (f32x4){0.f, 0.f, 0.f, 0.f};
    size_t reb = (size_t)(b * 24 + 2 * kx) * 64 * 128;
    size_t imb = (size_t)(b * 24 + 2 * kx + 1) * 64 * 128;
    int c = w * 16 + ln;
#pragma unroll
    for (int ks = 0; ks < 8; ++ks) {
        int k = ks * 32 + lg * 8;
        size_t boff = (ks < 4) ? (reb + (size_t)c * 128 + k) : (imb + (size_t)c * 128 + (k - 128));
        short8 bH = ld8(A2H + boff);
        short8 bL = ld8(A2L + boff);
#pragma unroll
        for (int m = 0; m < 3; ++m) {
            int aoff = (m * 16 + ln) * 256 + ks * 32 + lg * 8;
            short8 aH = ld8(TDH + aoff);
            short8 aL = ld8(TDL + aoff);
            MFMA3(acc[m], aH, aL, bH, bL);
        }
    }
    float* Hf = (float*)Hm;
#pragma unroll
    for (int m = 0; m < 3; ++m)
#pragma unroll
        for (int r = 0; r < 4; ++r) {
            int row = m * 16 + lg * 4 + r;           // 0..47
            int kt = row >> 1, p = row & 1;
            int mode = kt * 12 + kx;
            Hf[(((size_t)mode * 16 + b) * 64 + c) * 2 + p] = acc[m][r];
        }
}

// ---------------- per-mode channel mix (fp32) ----------------
__global__ __launch_bounds__(256) void k_mix(const float2* __restrict__ Hm, const float2* __restrict__ WtL,
                                             float2* __restrict__ Om) {
    __shared__ float2 hl[8 * 64];
    int bid = blockIdx.x, tid = threadIdx.x;
    int mode = bid >> 1, bh = bid & 1;
    const float2* hsrc = Hm + ((size_t)mode * 16 + bh * 8) * 64;
    for (int i = tid; i < 512; i += 256) hl[i] = hsrc[i];
    __syncthreads();
    int o = tid & 63, bg = tid >> 6;
    const float2* wp = WtL + (size_t)mode * 4096 + o;
    const float2* h0 = hl + (bg * 2) * 64;
    const float2* h1 = hl + (bg * 2 + 1) * 64;
    float a0r = 0.f, a0i = 0.f, a1r = 0.f, a1i = 0.f;
#pragma unroll 4
    for (int c = 0; c < 64; ++c) {
        float2 wv = wp[c * 64];
        float2 a0 = h0[c], a1 = h1[c];
        a0r += a0.x * wv.x - a0.y * wv.y;
        a0i += a0.x * wv.y + a0.y * wv.x;
        a1r += a1.x * wv.x - a1.y * wv.y;
        a1i += a1.x * wv.y + a1.y * wv.x;
    }
    int b0 = bh * 8 + bg * 2;
    Om[((size_t)(b0)*64 + o) * 288 + mode]       = make_float2(a0r, a0i);
    Om[((size_t)(b0 + 1) * 64 + o) * 288 + mode] = make_float2(a1r, a1i);
}

__global__ __launch_bounds__(256) void k_mix_raw(const float2* __restrict__ Hm,
                                                 const float* __restrict__ w1re, const float* __restrict__ w1im,
                                                 const float* __restrict__ w2re, const float* __restrict__ w2im,
                                                 float2* __restrict__ Om) {
    __shared__ float2 hl[8 * 64];
    int bid = blockIdx.x, tid = threadIdx.x;
    int mode = bid >> 1, bh = bid & 1;
    const float2* hsrc = Hm + ((size_t)mode * 16 + bh * 8) * 64;
    for (int i = tid; i < 512; i += 256) hl[i] = hsrc[i];
    __syncthreads();
    int kti = mode / 12, kx = mode - kti * 12;
    const float* re; const float* im; int ktw;
    if (kti < 12) { re = w1re; im = w1im; ktw = kti; }
    else          { re = w2re; im = w2im; ktw = kti - 12; }
    int off = ktw * 12 + kx;
    int o = tid & 63, bg = tid >> 6;
    const float2* h0 = hl + (bg * 2) * 64;
    const float2* h1 = hl + (bg * 2 + 1) * 64;
    float a0r = 0.f, a0i = 0.f, a1r = 0.f, a1i = 0.f;
    for (int c = 0; c < 64; ++c) {
        size_t widx = (size_t)(c * 64 + o) * 144 + off;
        float wr = re[widx], wi = im[widx];
        float2 a0 = h0[c], a1 = h1[c];
        a0r += a0.x * wr - a0.y * wi;
        a0i += a0.x * wi + a0.y * wr;
        a1r += a1.x * wr - a1.y * wi;
        a1i += a1.x * wi + a1.y * wr;
    }
    int b0 = bh * 8 + bg * 2;
    Om[((size_t)(b0)*64 + o) * 288 + mode]       = make_float2(a0r, a0i);
    Om[((size_t)(b0 + 1) * 64 + o) * 288 + mode] = make_float2(a1r, a1i);
}

// ---------------- inverse t-DFT: MFMA, split-bf16 output ----------------
// Bv[(b*64+o)*128+t][32]: out[t][col] = sum_k TI[t][k] * Om2T[col][k]
__global__ __launch_bounds__(256) void k_idftt2(const float2* __restrict__ Om,
                                                const unsigned short* __restrict__ TIH, const unsigned short* __restrict__ TIL,
                                                unsigned short* __restrict__ BvH, unsigned short* __restrict__ BvL) {
    __shared__ unsigned short OmH[32][72], OmL[32][72];
    int bo = blockIdx.x, tid = threadIdx.x;
    unsigned int* zh = (unsigned int*)&OmH[0][0];
    unsigned int* zl = (unsigned int*)&OmL[0][0];
    for (int i = tid; i < 1152; i += 256) { zh[i] = 0u; zl[i] = 0u; }
    __syncthreads();
    const float2* src = Om + (size_t)bo * 288;
    for (int i = tid; i < 288; i += 256) {
        int kt = i / 12, kx = i - kt * 12;
        float2 o = src[i];
        unsigned short h, l;
        split2(o.x, h, l);  OmH[2 * kx][2 * kt] = h;     OmL[2 * kx][2 * kt] = l;
        split2(o.y, h, l);  OmH[2 * kx][2 * kt + 1] = h; OmL[2 * kx][2 * kt + 1] = l;
                            OmH[2 * kx + 1][2 * kt] = h; OmL[2 * kx + 1][2 * kt] = l;
        split2(-o.x, h, l); OmH[2 * kx + 1][2 * kt + 1] = h; OmL[2 * kx + 1][2 * kt + 1] = l;
    }
    __syncthreads();
    int w = tid >> 6, lane = tid & 63, ln = lane & 15, lg = lane >> 4;
    f32x4 acc[2][2];
#pragma unroll
    for (int mi = 0; mi < 2; ++mi)
#pragma unroll
        for (int nt = 0; nt < 2; ++nt) acc[mi][nt] = (f32x4){0.f, 0.f, 0.f, 0.f};
#pragma unroll
    for (int ks = 0; ks < 2; ++ks) {
        short8 bH[2], bL[2];
#pragma unroll
        for (int nt = 0; nt < 2; ++nt) {
            int boff = (nt * 16 + ln) * 72 + ks * 32 + lg * 8;
            bH[nt] = ld8(&OmH[0][0] + boff);
            bL[nt] = ld8(&OmL[0][0] + boff);
        }
#pragma unroll
        for (int mi = 0; mi < 2; ++mi) {
            int mt = w * 2 + mi;
            int aoff = (mt * 16 + ln) * 64 + ks * 32 + lg * 8;
            short8 aH = ld8(TIH + aoff);
            short8 aL = ld8(TIL + aoff);
#pragma unroll
            for (int nt = 0; nt < 2; ++nt) { MFMA3(acc[mi][nt], aH, aL, bH[nt], bL[nt]); }
        }
    }
#pragma unroll
    for (int mi = 0; mi < 2; ++mi)
#pragma unroll
        for (int nt = 0; nt < 2; ++nt)
#pragma unroll
            for (int r = 0; r < 4; ++r) {
                int trow = (w * 2 + mi) * 16 + lg * 4 + r;
                int col = nt * 16 + ln;
                unsigned short h, l;
                split2(acc[mi][nt][r], h, l);
                size_t p = ((size_t)bo * 128 + trow) * 32 + col;
                BvH[p] = h; BvL[p] = l;
            }
}

// ---------------- conv + inv x-DFT + (gelu) + fused fwd x-DFT of the NEW h ----------------
// block=(b,t): D[o=64][x=128] = sum_c W[o][c] hT[x][c] + sum_k Bv[o][k] TiX[x][k]
// epilogue: +bias, gelu (l<3), write hT; FUSE: h tile -> LDS f32 -> x-DFT MFMA -> A2 split.
template <int DOGELU, int FUSE>
__global__ __launch_bounds__(256) void k_conv3(unsigned short* __restrict__ hTH, unsigned short* __restrict__ hTL,
                                               const unsigned short* __restrict__ WH, const unsigned short* __restrict__ WL,
                                               const unsigned short* __restrict__ BvH, const unsigned short* __restrict__ BvL,
                                               const unsigned short* __restrict__ TiXH, const unsigned short* __restrict__ TiXL,
                                               const unsigned short* __restrict__ TfH, const unsigned short* __restrict__ TfL,
                                               unsigned short* __restrict__ A2H, unsigned short* __restrict__ A2L,
                                               const float* __restrict__ bconv) {
    __shared__ float hsf[64][132];
    int bid = blockIdx.x, tid = threadIdx.x;
    int t = bid & 127, b = bid >> 7;
    int w = tid >> 6, lane = tid & 63, ln = lane & 15, lg = lane >> 4;
    size_t btbase = (size_t)(b * 128 + t) * 128 * 64;
    f32x4 acc[8];
#pragma unroll
    for (int nx = 0; nx < 8; ++nx) acc[nx] = (f32x4){0.f, 0.f, 0.f, 0.f};
    // main: K = c (64)
#pragma unroll
    for (int kt = 0; kt < 2; ++kt) {
        int aoff = (w * 16 + ln) * 64 + kt * 32 + lg * 8;
        short8 aH = ld8(WH + aoff);
        short8 aL = ld8(WL + aoff);
#pragma unroll
        for (int nx = 0; nx < 8; ++nx) {
            size_t boff = btbase + (size_t)(nx * 16 + ln) * 64 + kt * 32 + lg * 8;
            short8 bH = ld8(hTH + boff);
            short8 bL = ld8(hTL + boff);
            MFMA3(acc[nx], aH, aL, bH, bL);
        }
    }
    // spectral: K' = 24 (padded 32)
    {
        size_t aoff = ((size_t)(b * 64 + w * 16 + ln) * 128 + t) * 32 + lg * 8;
        short8 aH = ld8(BvH + aoff);
        short8 aL = ld8(BvL + aoff);
#pragma unroll
        for (int nx = 0; nx < 8; ++nx) {
            int boff = (nx * 16 + ln) * 32 + lg * 8;
            short8 bH = ld8(TiXH + boff);
            short8 bL = ld8(TiXL + boff);
            MFMA3(acc[nx], aH, aL, bH, bL);
        }
    }
    __syncthreads();   // all hT reads complete before in-place update
    int o0 = w * 16 + lg * 4;
    float bc0 = bconv[o0], bc1 = bconv[o0 + 1], bc2 = bconv[o0 + 2], bc3 = bconv[o0 + 3];
#pragma unroll
    for (int nx = 0; nx < 8; ++nx) {
        int x = nx * 16 + ln;
        float v0 = acc[nx][0] + bc0;
        float v1 = acc[nx][1] + bc1;
        float v2 = acc[nx][2] + bc2;
        float v3 = acc[nx][3] + bc3;
        if (DOGELU) { v0 = gelu_erf(v0); v1 = gelu_erf(v1); v2 = gelu_erf(v2); v3 = gelu_erf(v3); }
        unsigned short hh[4], ll[4];
        split2(v0, hh[0], ll[0]); split2(v1, hh[1], ll[1]);
        split2(v2, hh[2], ll[2]); split2(v3, hh[3], ll[3]);
        size_t trow = btbase + (size_t)x * 64 + o0;
        *reinterpret_cast<uint2*>(&hTH[trow]) =
            make_uint2((unsigned)hh[0] | ((unsigned)hh[1] << 16), (unsigned)hh[2] | ((unsigned)hh[3] << 16));
        *reinterpret_cast<uint2*>(&hTL[trow]) =
            make_uint2((unsigned)ll[0] | ((unsigned)ll[1] << 16), (unsigned)ll[2] | ((unsigned)ll[3] << 16));
        if (FUSE) {
            hsf[o0 + 0][x] = v0; hsf[o0 + 1][x] = v1;
            hsf[o0 + 2][x] = v2; hsf[o0 + 3][x] = v3;
        }
    }
    if (FUSE) {
        __syncthreads();
        int mw = w & 1, ng = (w >> 1) * 2;
        f32x4 acc2[2];
        acc2[0] = (f32x4){0.f, 0.f, 0.f, 0.f};
        acc2[1] = (f32x4){0.f, 0.f, 0.f, 0.f};
#pragma unroll
        for (int kt = 0; kt < 4; ++kt) {
            int aoff = (mw * 16 + ln) * 128 + kt * 32 + lg * 8;
            short8 aH = ld8(TfH + aoff);
            short8 aL = ld8(TfL + aoff);
#pragma unroll
            for (int j = 0; j < 2; ++j) {
                int c = (ng + j) * 16 + ln;
                float4 f0 = *reinterpret_cast<const float4*>(&hsf[c][kt * 32 + lg * 8]);
                float4 f1 = *reinterpret_cast<const float4*>(&hsf[c][kt * 32 + lg * 8 + 4]);
                short8 bH, bL;
                unsigned short h, l;
                split2(f0.x, h, l); bH[0] = (short)h; bL[0] = (short)l;
                split2(f0.y, h, l); bH[1] = (short)h; bL[1] = (short)l;
                split2(f0.z, h, l); bH[2] = (short)h; bL[2] = (short)l;
                split2(f0.w, h, l); bH[3] = (short)h; bL[3] = (short)l;
                split2(f1.x, h, l); bH[4] = (short)h; bL[4] = (short)l;
                split2(f1.y, h, l); bH[5] = (short)h; bL[5] = (short)l;
                split2(f1.z, h, l); bH[6] = (short)h; bL[6] = (short)l;
                split2(f1.w, h, l); bH[7] = (short)h; bL[7] = (short)l;
                MFMA3(acc2[j], aH, aL, bH, bL);
            }
        }
#pragma unroll
        for (int j = 0; j < 2; ++j) {
            int c = (ng + j) * 16 + ln;
#pragma unroll
            for (int r = 0; r < 4; ++r) {
                int col = mw * 16 + lg * 4 + r;
                if (col < 24) {
                    unsigned short h, l;
                    split2(acc2[j][r], h, l);
                    size_t addr = ((size_t)(b * 24 + col) * 64 + c) * 128 + t;
                    A2H[addr] = h; A2L[addr] = l;
                }
            }
        }
    }
}

// ---------------- head: fc1 + gelu + fc2, zero-LDS MFMA ----------------
__global__ __launch_bounds__(256) void k_head2(const unsigned short* __restrict__ hTH, const unsigned short* __restrict__ hTL,
                                               const unsigned short* __restrict__ F1H, const unsigned short* __restrict__ F1L,
                                               const float* __restrict__ b1, const float* __restrict__ w2,
                                               const float* __restrict__ b2, float* __restrict__ out) {
    __shared__ float red[16][66];
    int bid = blockIdx.x, tid = threadIdx.x;
    int xh = bid & 1, t = (bid >> 1) & 127, b = bid >> 8;
    int w = tid >> 6, lane = tid & 63, ln = lane & 15, lg = lane >> 4;
    f32x4 acc[2][4];
#pragma unroll
    for (int s = 0; s < 2; ++s)
#pragma unroll
        for (int nx = 0; nx < 4; ++nx) acc[s][nx] = (f32x4){0.f, 0.f, 0.f, 0.f};
    size_t btbase = ((size_t)(b * 128 + t) * 128 + xh * 64) * 64;
#pragma unroll
    for (int kt = 0; kt < 2; ++kt) {
        short8 bH[4], bL[4];
#pragma unroll
        for (int nx = 0; nx < 4; ++nx) {
            size_t boff = btbase + (size_t)(nx * 16 + ln) * 64 + kt * 32 + lg * 8;
            bH[nx] = ld8(hTH + boff);
            bL[nx] = ld8(hTL + boff);
        }
#pragma unroll
        for (int s = 0; s < 2; ++s) {
            int aoff = ((w * 2 + s) * 16 + ln) * 64 + kt * 32 + lg * 8;
            short8 aH = ld8(F1H + aoff);
            short8 aL = ld8(F1L + aoff);
#pragma unroll
            for (int nx = 0; nx < 4; ++nx) { MFMA3(acc[s][nx], aH, aL, bH[nx], bL[nx]); }
        }
    }
    float p[4] = {0.f, 0.f, 0.f, 0.f};
#pragma unroll
    for (int s = 0; s < 2; ++s)
#pragma unroll
        for (int r = 0; r < 4; ++r) {
            int d = (w * 2 + s) * 16 + lg * 4 + r;
            float bb = b1[d], wk = w2[d];
#pragma unroll
            for (int nx = 0; nx < 4; ++nx) {
                float v = acc[s][nx][r] + bb;
                p[nx] += gelu_erf(v) * wk;
            }
        }
#pragma unroll
    for (int nx = 0; nx < 4; ++nx) red[w * 4 + lg][nx * 16 + ln] = p[nx];
    __syncthreads();
    if (tid < 64) {
        float s = 0.f;
#pragma unroll
        for (int g = 0; g < 16; ++g) s += red[g][tid];
        out[((size_t)b * 128 + t) * 128 + xh * 64 + tid] = s + b2[0];
    }
}

extern "C" void kernel_launch(void* const* d_in, const int* in_sizes, int n_in,
                              void* d_out, int out_size, void* d_ws, size_t ws_size,
                              hipStream_t stream) {
    const float* ts    = (const float*)d_in[0];
    const float* xs    = (const float*)d_in[1];
    const float* u0    = (const float*)d_in[2];
    const float* fc0_w = (const float*)d_in[3];
    const float* fc0_b = (const float*)d_in[4];
    const float* w1re  = (const float*)d_in[5];
    const float* w1im  = (const float*)d_in[6];
    const float* w2re  = (const float*)d_in[7];
    const float* w2im  = (const float*)d_in[8];
    const float* wconv = (const float*)d_in[9];
    const float* bconv = (const float*)d_in[10];
    const float* fc1w  = (const float*)d_in[11];
    const float* fc1b  = (const float*)d_in[12];
    const float* fc2w  = (const float*)d_in[13];
    const float* fc2b  = (const float*)d_in[14];
    float* out = (float*)d_out;

    char* ws = (char*)d_ws;
    size_t off = 0;
    auto alloc = [&](size_t bytes) -> char* {
        char* p = ws + off;
        off = (off + bytes + 255) & ~(size_t)255;
        return p;
    };
    unsigned short* hTH = (unsigned short*)alloc(33554432);   // [16*128*128][64]
    unsigned short* hTL = (unsigned short*)alloc(33554432);
    unsigned short* A2H = (unsigned short*)alloc(6291456);    // [16][24][64][128]
    unsigned short* A2L = (unsigned short*)alloc(6291456);
    float2* Hm = (float2*)alloc(2359296);                     // [288][16][64]
    float2* Om = (float2*)alloc(2359296);                     // [16][64][288]
    unsigned short* BvH = (unsigned short*)alloc(8388608);    // [16*64*128][32]
    unsigned short* BvL = (unsigned short*)alloc(8388608);
    float* U   = (float*)alloc(4096);
    float2* Sx = (float2*)alloc(256);
    float2* St = (float2*)alloc(256);
    unsigned short* TfH  = (unsigned short*)alloc(8192);
    unsigned short* TfL  = (unsigned short*)alloc(8192);
    unsigned short* TiXH = (unsigned short*)alloc(8192);
    unsigned short* TiXL = (unsigned short*)alloc(8192);
    unsigned short* TDH  = (unsigned short*)alloc(24576);
    unsigned short* TDL  = (unsigned short*)alloc(24576);
    unsigned short* TIH  = (unsigned short*)alloc(16384);
    unsigned short* TIL  = (unsigned short*)alloc(16384);
    unsigned short* WH   = (unsigned short*)alloc(32768);
    unsigned short* WL   = (unsigned short*)alloc(32768);
    unsigned short* F1H  = (unsigned short*)alloc(16384);
    unsigned short* F1L  = (unsigned short*)alloc(16384);
    size_t base_need = off;
    if (ws_size < base_need) return;
    float2* Wt = (float2*)alloc(37748736);                    // [4][288][64][64]
    bool use_wt = (ws_size >= off);

    k_tables2<<<1, 256, 0, stream>>>(TfH, TfL, TiXH, TiXL, TDH, TDL, TIH, TIL);
    k_spec<<<1, 64, 0, stream>>>(xs, ts, Sx, St);
    k_u<<<16, 64, 0, stream>>>(u0, fc0_w, fc0_b, U);
    k_wprep<<<64, 256, 0, stream>>>(wconv, fc1w, WH, WL, F1H, F1L);
    k_fc0t<<<2048, 256, 0, stream>>>(xs, ts, fc0_w, U, hTH, hTL);
    k_hm0<<<288, 256, 0, stream>>>(fc0_w, U, Sx, St, Hm);
    if (use_wt)
        k_wt<<<512, 256, 0, stream>>>(w1re, w1im, w2re, w2im, Wt);

    for (int l = 0; l < 4; ++l) {
        if (l > 0)
            k_dftt2<<<192, 256, 0, stream>>>(A2H, A2L, TDH, TDL, Hm);
        if (use_wt)
            k_mix<<<576, 256, 0, stream>>>(Hm, Wt + (size_t)l * 288 * 4096, Om);
        else
            k_mix_raw<<<576, 256, 0, stream>>>(Hm, w1re + (size_t)l * 589824, w1im + (size_t)l * 589824,
                                               w2re + (size_t)l * 589824, w2im + (size_t)l * 589824, Om);
        k_idftt2<<<1024, 256, 0, stream>>>(Om, TIH, TIL, BvH, BvL);
        if (l < 3)
            k_conv3<1, 1><<<2048, 256, 0, stream>>>(hTH, hTL, WH + l * 4096, WL + l * 4096,
                                                    BvH, BvL, TiXH, TiXL, TfH, TfL, A2H, A2L, bconv + l * 64);
        else
            k_conv3<0, 0><<<2048, 256, 0, stream>>>(hTH, hTL, WH + l * 4096, WL + l * 4096,
                                                    BvH, BvL, TiXH, TiXL, TfH, TfL, A2H, A2L, bconv + l * 64);
    }
    k_head2<<<4096, 256, 0, stream>>>(hTH, hTL, F1H, F1L, fc1b, fc2w, fc2b, out);
}

// Round 6
// 610.653 us; speedup vs baseline: 1.2801x; 1.1867x over previous
//
#include <hip/hip_runtime.h>
#include <math.h>

// FNO: N=16, H=64, NT=128, NX=128, M=12, DH=128, DIN=128
// R6: state = hT[b,t,x][c] split-bf16 (hi/lo). Layer-0 fully analytic (no hT read,
// no fc0 kernel). Head fused into conv layer 3. A2 layout [b][col][t][c] with
// coalesced LDS-staged writes; dftt2 transposes in LDS.

typedef __attribute__((ext_vector_type(8))) short short8;
typedef __attribute__((ext_vector_type(4))) float f32x4;

__device__ inline unsigned short bf16rn(float v) {
    unsigned int b = __float_as_uint(v);
    return (unsigned short)((b + 0x7FFFu + ((b >> 16) & 1u)) >> 16);
}
__device__ inline void split2(float v, unsigned short& h, unsigned short& l) {
    h = bf16rn(v);
    float hf = __uint_as_float((unsigned int)h << 16);
    l = bf16rn(v - hf);
}
__device__ inline short8 ld8(const unsigned short* p) {
    return *reinterpret_cast<const short8*>(p);
}
__device__ inline float gelu_erf(float v) {
    return 0.5f * v * (1.0f + erff(v * 0.70710678118654752f));
}
#define MFMA3(accv, aH, aL, bH, bL) \
    accv = __builtin_amdgcn_mfma_f32_16x16x32_bf16(aH, bH, accv, 0, 0, 0); \
    accv = __builtin_amdgcn_mfma_f32_16x16x32_bf16(aH, bL, accv, 0, 0, 0); \
    accv = __builtin_amdgcn_mfma_f32_16x16x32_bf16(aL, bH, accv, 0, 0, 0);

#define STEPC 0.049087385212340519350f  // 2*pi/128

// ---------------- tables ----------------
// Tf  [32][128]: row 2kx=cos, 2kx+1=-sin (fwd x-DFT A-op; rows 24-31 zero)
// TiX [128][32]: col 2kx=w*cos, 2kx+1=-w*sin, w=(kx?2:1)/16384
// TD  [2][48][128]: fwd t-DFT A-op per input phase q: q=0(re): 2kt=cos,2kt+1=-sin;
//                   q=1(im): 2kt=sin, 2kt+1=cos
// TI  [128][64]: inv t-DFT A-op; col 2kt=cos, 2kt+1=-sin (cols 48-63 zero)
__global__ __launch_bounds__(256) void k_tables2(unsigned short* TfH, unsigned short* TfL,
                                                 unsigned short* TiXH, unsigned short* TiXL,
                                                 unsigned short* TDH, unsigned short* TDL,
                                                 unsigned short* TIH, unsigned short* TIL) {
    int tid = threadIdx.x;
    unsigned short h, l;
    for (int i = tid; i < 32 * 128; i += 256) {
        int row = i >> 7, x = i & 127;
        float v = 0.f;
        if (row < 24) {
            int kx = row >> 1;
            float th = ((kx * x) & 127) * STEPC;
            v = (row & 1) ? -sinf(th) : cosf(th);
        }
        split2(v, h, l); TfH[i] = h; TfL[i] = l;
    }
    for (int i = tid; i < 128 * 32; i += 256) {
        int x = i >> 5, col = i & 31;
        float v = 0.f;
        if (col < 24) {
            int kx = col >> 1;
            float th = ((kx * x) & 127) * STEPC;
            float w = (kx == 0 ? 1.0f : 2.0f) / 16384.0f;
            v = (col & 1) ? -w * sinf(th) : w * cosf(th);
        }
        split2(v, h, l); TiXH[i] = h; TiXL[i] = l;
    }
    for (int i = tid; i < 2 * 48 * 128; i += 256) {
        int q = i >> 12;                    // 48*128 = 6144 per phase
        int rem = i & 6143;
        int row = rem >> 7, t = rem & 127;
        int kt = row >> 1;
        int f = (kt < 12) ? kt : (kt + 104);
        float th = ((f * t) & 127) * STEPC;
        float c = cosf(th), s = sinf(th);
        float v;
        if (q == 0) v = (row & 1) ? -s : c;
        else        v = (row & 1) ?  c : s;
        split2(v, h, l); TDH[i] = h; TDL[i] = l;
    }
    for (int i = tid; i < 128 * 64; i += 256) {
        int t = i >> 6, col = i & 63;
        float v = 0.f;
        if (col < 48) {
            int kt = col >> 1;
            int f = (kt < 12) ? kt : (kt + 104);
            float th = ((f * t) & 127) * STEPC;
            v = (col & 1) ? -sinf(th) : cosf(th);
        }
        split2(v, h, l); TIH[i] = h; TIL[i] = l;
    }
}

// spectral sums: Sx[kx]=sum_x xs e^{-i th}, St[kt]=sum_t ts e^{-i th}
__global__ void k_spec(const float* __restrict__ xs, const float* __restrict__ ts,
                       float2* __restrict__ Sx, float2* __restrict__ St) {
    int tid = threadIdx.x;
    if (tid < 12) {
        float re = 0.f, im = 0.f;
        for (int x = 0; x < 128; ++x) {
            float th = ((tid * x) & 127) * STEPC;
            re += xs[x] * cosf(th); im -= xs[x] * sinf(th);
        }
        Sx[tid] = make_float2(re, im);
    } else if (tid >= 32 && tid < 56) {
        int kt = tid - 32;
        int f = (kt < 12) ? kt : (kt + 104);
        float re = 0.f, im = 0.f;
        for (int t = 0; t < 128; ++t) {
            float th = ((f * t) & 127) * STEPC;
            re += ts[t] * cosf(th); im -= ts[t] * sinf(th);
        }
        St[kt] = make_float2(re, im);
    }
}

__global__ void k_u(const float* __restrict__ u0, const float* __restrict__ w,
                    const float* __restrict__ bias, float* __restrict__ U) {
    int b = blockIdx.x, c = threadIdx.x;
    float acc = bias[c];
    const float* wr = w + c * 130 + 2;
    const float* ur = u0 + b * 128;
    for (int d = 0; d < 128; ++d) acc += ur[d] * wr[d];
    U[b * 64 + c] = acc;
}

// pre-split wconv [4][64][64] and fc1w [128][64]
__global__ __launch_bounds__(256) void k_wprep(const float* __restrict__ wconv, const float* __restrict__ fc1w,
                                               unsigned short* WH, unsigned short* WL,
                                               unsigned short* F1H, unsigned short* F1L) {
    int i = blockIdx.x * 256 + threadIdx.x;
    if (i < 16384) split2(wconv[i], WH[i], WL[i]);
    if (i < 8192)  split2(fc1w[i], F1H[i], F1L[i]);
}

// analytic layer-0 pointwise path: Ww0[o]=W0·w0c, Ww1[o]=W0·w1c, WU[b][o]=bconv0[o]+W0·U[b]
__global__ void k_cw(const float* __restrict__ wconv, const float* __restrict__ bconv,
                     const float* __restrict__ fc0_w, const float* __restrict__ U,
                     float* __restrict__ Ww0, float* __restrict__ Ww1, float* __restrict__ WU) {
    int b = blockIdx.x, o = threadIdx.x;
    const float* wr = wconv + o * 64;
    float au = bconv[o];
    const float* ur = U + b * 64;
    for (int c = 0; c < 64; ++c) au += wr[c] * ur[c];
    WU[b * 64 + o] = au;
    if (b == 0) {
        float a0 = 0.f, a1 = 0.f;
        for (int c = 0; c < 64; ++c) {
            a0 += wr[c] * fc0_w[c * 130];
            a1 += wr[c] * fc0_w[c * 130 + 1];
        }
        Ww0[o] = a0; Ww1[o] = a1;
    }
}

// analytic layer-0 Hm: support only on kt=0 or kx=0 axes
__global__ __launch_bounds__(256) void k_hm0(const float* __restrict__ fc0_w, const float* __restrict__ U,
                                             const float2* __restrict__ Sx, const float2* __restrict__ St,
                                             float2* __restrict__ Hm) {
    __shared__ float w0s[64], w1s[64];
    int mode = blockIdx.x, tid = threadIdx.x;
    int kt = mode / 12, kx = mode - kt * 12;
    if (tid < 64) { w0s[tid] = fc0_w[tid * 130]; w1s[tid] = fc0_w[tid * 130 + 1]; }
    __syncthreads();
    float2 sx = Sx[kx], st = St[kt];
    for (int i = tid; i < 1024; i += 256) {
        int b = i >> 6, c = i & 63;
        float re = 0.f, im = 0.f;
        if (kt == 0) { re += 128.f * w0s[c] * sx.x; im += 128.f * w0s[c] * sx.y; }
        if (kx == 0) { re += 128.f * w1s[c] * st.x; im += 128.f * w1s[c] * st.y; }
        if (kt == 0 && kx == 0) re += 16384.f * U[b * 64 + c];
        Hm[((size_t)mode * 16 + b) * 64 + c] = make_float2(re, im);
    }
}

// ---------------- weight pre-transpose for fp32 k_mix ----------------
__global__ __launch_bounds__(256) void k_wt(const float* __restrict__ w1re, const float* __restrict__ w1im,
                                            const float* __restrict__ w2re, const float* __restrict__ w2im,
                                            float2* __restrict__ Wt) {
    __shared__ float ldsre[32 * 145];
    __shared__ float ldsim[32 * 145];
    int bid = blockIdx.x, tid = threadIdx.x;
    int c = bid & 63, tbl = (bid >> 6) & 1, l = bid >> 7;
    const float* re = (tbl ? w2re : w1re) + (size_t)((l * 64 + c) * 64) * 144;
    const float* im = (tbl ? w2im : w1im) + (size_t)((l * 64 + c) * 64) * 144;
    int moff = tbl * 144;
    for (int half = 0; half < 2; ++half) {
        __syncthreads();
        for (int i = tid; i < 32 * 144; i += 256) {
            int o = i / 144, m = i - o * 144;
            ldsre[o * 145 + m] = re[(half * 32 + o) * 144 + m];
            ldsim[o * 145 + m] = im[(half * 32 + o) * 144 + m];
        }
        __syncthreads();
        for (int i = tid; i < 32 * 144; i += 256) {
            int mode = i >> 5, o = i & 31;
            Wt[((size_t)(l * 288 + moff + mode) * 64 + c) * 64 + half * 32 + o] =
                make_float2(ldsre[o * 145 + mode], ldsim[o * 145 + mode]);
        }
    }
}

// ---------------- forward t-DFT: LDS-transposed staging + MFMA ----------------
// A2 layout [b][col24][t][c]; block (b,kx); D[2kt+p][c] = sum_q sum_t TD[q][2kt+p][t]*A2[b][2kx+q][t][c]
__global__ __launch_bounds__(256) void k_dftt2(const unsigned short* __restrict__ A2H, const unsigned short* __restrict__ A2L,
                                               const unsigned short* __restrict__ TDH, const unsigned short* __restrict__ TDL,
                                               float2* __restrict__ Hm) {
    __shared__ unsigned short sH[64][136], sL[64][136];
    int bid = blockIdx.x, tid = threadIdx.x;
    int b = bid / 12, kx = bid - b * 12;
    int w = tid >> 6, lane = tid & 63, ln = lane & 15, lg = lane >> 4;
    f32x4 acc[3];
#pragma unroll
    for (int m = 0; m < 3; ++m) acc[m] = (f32x4){0.f, 0.f, 0.f, 0.f};
#pragma unroll
    for (int q = 0; q < 2; ++q) {
        if (q) __syncthreads();                     // prev MFMA reads done
        int col = 2 * kx + q;
        const unsigned short* srcH = A2H + (size_t)(b * 24 + col) * 128 * 64;
        const unsigned short* srcL = A2L + (size_t)(b * 24 + col) * 128 * 64;
        for (int i = tid; i < 1024; i += 256) {
            int t = i >> 3, c0 = (i & 7) * 8;
            uint4 vh = *reinterpret_cast<const uint4*>(srcH + t * 64 + c0);
            uint4 vl = *reinterpret_cast<const uint4*>(srcL + t * 64 + c0);
            const unsigned short* ph = (const unsigned short*)&vh;
            const unsigned short* pl = (const unsigned short*)&vl;
#pragma unroll
            for (int j = 0; j < 8; ++j) {
                sH[c0 + j][t] = ph[j];
                sL[c0 + j][t] = pl[j];
            }
        }
        __syncthreads();
#pragma unroll
        for (int ks = 0; ks < 4; ++ks) {
            short8 bH = ld8(&sH[w * 16 + ln][ks * 32 + lg * 8]);
            short8 bL = ld8(&sL[w * 16 + ln][ks * 32 + lg * 8]);
#pragma unroll
            for (int m = 0; m < 3; ++m) {
                int aoff = (q * 48 + m * 16 + ln) * 128 + ks * 32 + lg * 8;
                short8 aH = ld8(TDH + aoff);
                short8 aL = ld8(TDL + aoff);
                MFMA3(acc[m], aH, aL, bH, bL);
            }
        }
    }
    float* Hf = (float*)Hm;
    int c = w * 16 + ln;
#pragma unroll
    for (int m = 0; m < 3; ++m)
#pragma unroll
        for (int r = 0; r < 4; ++r) {
            int row = m * 16 + lg * 4 + r;
            int kt = row >> 1, pp = row & 1;
            Hf[(((size_t)(kt * 12 + kx) * 16 + b) * 64 + c) * 2 + pp] = acc[m][r];
        }
}

// ---------------- per-mode channel mix (fp32) ----------------
__global__ __launch_bounds__(256) void k_mix(const float2* __restrict__ Hm, const float2* __restrict__ WtL,
                                             float2* __restrict__ Om) {
    __shared__ float2 hl[8 * 64];
    int bid = blockIdx.x, tid = threadIdx.x;
    int mode = bid >> 1, bh = bid & 1;
    const float2* hsrc = Hm + ((size_t)mode * 16 + bh * 8) * 64;
    for (int i = tid; i < 512; i += 256) hl[i] = hsrc[i];
    __syncthreads();
    int o = tid & 63, bg = tid >> 6;
    const float2* wp = WtL + (size_t)mode * 4096 + o;
    const float2* h0 = hl + (bg * 2) * 64;
    const float2* h1 = hl + (bg * 2 + 1) * 64;
    float a0r = 0.f, a0i = 0.f, a1r = 0.f, a1i = 0.f;
#pragma unroll 4
    for (int c = 0; c < 64; ++c) {
        float2 wv = wp[c * 64];
        float2 a0 = h0[c], a1 = h1[c];
        a0r += a0.x * wv.x - a0.y * wv.y;
        a0i += a0.x * wv.y + a0.y * wv.x;
        a1r += a1.x * wv.x - a1.y * wv.y;
        a1i += a1.x * wv.y + a1.y * wv.x;
    }
    int b0 = bh * 8 + bg * 2;
    Om[((size_t)(b0)*64 + o) * 288 + mode]       = make_float2(a0r, a0i);
    Om[((size_t)(b0 + 1) * 64 + o) * 288 + mode] = make_float2(a1r, a1i);
}

__global__ __launch_bounds__(256) void k_mix_raw(const float2* __restrict__ Hm,
                                                 const float* __restrict__ w1re, const float* __restrict__ w1im,
                                                 const float* __restrict__ w2re, const float* __restrict__ w2im,
                                                 float2* __restrict__ Om) {
    __shared__ float2 hl[8 * 64];
    int bid = blockIdx.x, tid = threadIdx.x;
    int mode = bid >> 1, bh = bid & 1;
    const float2* hsrc = Hm + ((size_t)mode * 16 + bh * 8) * 64;
    for (int i = tid; i < 512; i += 256) hl[i] = hsrc[i];
    __syncthreads();
    int kti = mode / 12, kx = mode - kti * 12;
    const float* re; const float* im; int ktw;
    if (kti < 12) { re = w1re; im = w1im; ktw = kti; }
    else          { re = w2re; im = w2im; ktw = kti - 12; }
    int off = ktw * 12 + kx;
    int o = tid & 63, bg = tid >> 6;
    const float2* h0 = hl + (bg * 2) * 64;
    const float2* h1 = hl + (bg * 2 + 1) * 64;
    float a0r = 0.f, a0i = 0.f, a1r = 0.f, a1i = 0.f;
    for (int c = 0; c < 64; ++c) {
        size_t widx = (size_t)(c * 64 + o) * 144 + off;
        float wr = re[widx], wi = im[widx];
        float2 a0 = h0[c], a1 = h1[c];
        a0r += a0.x * wr - a0.y * wi;
        a0i += a0.x * wi + a0.y * wr;
        a1r += a1.x * wr - a1.y * wi;
        a1i += a1.x * wi + a1.y * wr;
    }
    int b0 = bh * 8 + bg * 2;
    Om[((size_t)(b0)*64 + o) * 288 + mode]       = make_float2(a0r, a0i);
    Om[((size_t)(b0 + 1) * 64 + o) * 288 + mode] = make_float2(a1r, a1i);
}

// ---------------- inverse t-DFT: MFMA, split-bf16 output ----------------
__global__ __launch_bounds__(256) void k_idftt2(const float2* __restrict__ Om,
                                                const unsigned short* __restrict__ TIH, const unsigned short* __restrict__ TIL,
                                                unsigned short* __restrict__ BvH, unsigned short* __restrict__ BvL) {
    __shared__ unsigned short OmH[32][72], OmL[32][72];
    int bo = blockIdx.x, tid = threadIdx.x;
    unsigned int* zh = (unsigned int*)&OmH[0][0];
    unsigned int* zl = (unsigned int*)&OmL[0][0];
    for (int i = tid; i < 1152; i += 256) { zh[i] = 0u; zl[i] = 0u; }
    __syncthreads();
    const float2* src = Om + (size_t)bo * 288;
    for (int i = tid; i < 288; i += 256) {
        int kt = i / 12, kx = i - kt * 12;
        float2 o = src[i];
        unsigned short h, l;
        split2(o.x, h, l);  OmH[2 * kx][2 * kt] = h;     OmL[2 * kx][2 * kt] = l;
        split2(o.y, h, l);  OmH[2 * kx][2 * kt + 1] = h; OmL[2 * kx][2 * kt + 1] = l;
                            OmH[2 * kx + 1][2 * kt] = h; OmL[2 * kx + 1][2 * kt] = l;
        split2(-o.x, h, l); OmH[2 * kx + 1][2 * kt + 1] = h; OmL[2 * kx + 1][2 * kt + 1] = l;
    }
    __syncthreads();
    int w = tid >> 6, lane = tid & 63, ln = lane & 15, lg = lane >> 4;
    f32x4 acc[2][2];
#pragma unroll
    for (int mi = 0; mi < 2; ++mi)
#pragma unroll
        for (int nt = 0; nt < 2; ++nt) acc[mi][nt] = (f32x4){0.f, 0.f, 0.f, 0.f};
#pragma unroll
    for (int ks = 0; ks < 2; ++ks) {
        short8 bH[2], bL[2];
#pragma unroll
        for (int nt = 0; nt < 2; ++nt) {
            int boff = (nt * 16 + ln) * 72 + ks * 32 + lg * 8;
            bH[nt] = ld8(&OmH[0][0] + boff);
            bL[nt] = ld8(&OmL[0][0] + boff);
        }
#pragma unroll
        for (int mi = 0; mi < 2; ++mi) {
            int aoff = ((w * 2 + mi) * 16 + ln) * 64 + ks * 32 + lg * 8;
            short8 aH = ld8(TIH + aoff);
            short8 aL = ld8(TIL + aoff);
#pragma unroll
            for (int nt = 0; nt < 2; ++nt) { MFMA3(acc[mi][nt], aH, aL, bH[nt], bL[nt]); }
        }
    }
#pragma unroll
    for (int mi = 0; mi < 2; ++mi)
#pragma unroll
        for (int nt = 0; nt < 2; ++nt)
#pragma unroll
            for (int r = 0; r < 4; ++r) {
                int trow = (w * 2 + mi) * 16 + lg * 4 + r;
                int col = nt * 16 + ln;
                unsigned short h, l;
                split2(acc[mi][nt][r], h, l);
                size_t p = ((size_t)bo * 128 + trow) * 32 + col;
                BvH[p] = h; BvL[p] = l;
            }
}

// ---------------- conv (mid / layer0) + inv x-DFT + gelu + fused fwd x-DFT ----------------
// AFFINE=1: layer 0, pointwise part analytic (no hT read). Both write hT + A2.
template <int AFFINE>
__global__ __launch_bounds__(256) void k_conv_mid(unsigned short* __restrict__ hTH, unsigned short* __restrict__ hTL,
                                                  const unsigned short* __restrict__ WH, const unsigned short* __restrict__ WL,
                                                  const unsigned short* __restrict__ BvH, const unsigned short* __restrict__ BvL,
                                                  const unsigned short* __restrict__ TiXH, const unsigned short* __restrict__ TiXL,
                                                  const unsigned short* __restrict__ TfH, const unsigned short* __restrict__ TfL,
                                                  unsigned short* __restrict__ A2H, unsigned short* __restrict__ A2L,
                                                  const float* __restrict__ bconv,
                                                  const float* __restrict__ xs, const float* __restrict__ ts,
                                                  const float* __restrict__ Ww0, const float* __restrict__ Ww1,
                                                  const float* __restrict__ WU) {
    __shared__ float hsf[64][132];
    int bid = blockIdx.x, tid = threadIdx.x;
    int t = bid & 127, b = bid >> 7;
    int w = tid >> 6, lane = tid & 63, ln = lane & 15, lg = lane >> 4;
    size_t btbase = (size_t)(b * 128 + t) * 128 * 64;
    f32x4 acc[8];
#pragma unroll
    for (int nx = 0; nx < 8; ++nx) acc[nx] = (f32x4){0.f, 0.f, 0.f, 0.f};
    if (!AFFINE) {
#pragma unroll
        for (int kt = 0; kt < 2; ++kt) {
            int aoff = (w * 16 + ln) * 64 + kt * 32 + lg * 8;
            short8 aH = ld8(WH + aoff);
            short8 aL = ld8(WL + aoff);
#pragma unroll
            for (int nx = 0; nx < 8; ++nx) {
                size_t boff = btbase + (size_t)(nx * 16 + ln) * 64 + kt * 32 + lg * 8;
                short8 bH = ld8(hTH + boff);
                short8 bL = ld8(hTL + boff);
                MFMA3(acc[nx], aH, aL, bH, bL);
            }
        }
    }
    {
        size_t aoff = ((size_t)(b * 64 + w * 16 + ln) * 128 + t) * 32 + lg * 8;
        short8 aH = ld8(BvH + aoff);
        short8 aL = ld8(BvL + aoff);
#pragma unroll
        for (int nx = 0; nx < 8; ++nx) {
            int boff = (nx * 16 + ln) * 32 + lg * 8;
            short8 bH = ld8(TiXH + boff);
            short8 bL = ld8(TiXL + boff);
            MFMA3(acc[nx], aH, aL, bH, bL);
        }
    }
    __syncthreads();   // hT reads complete before in-place update
    int o0 = w * 16 + lg * 4;
    float ad0, ad1, ad2, ad3, w00 = 0.f, w01 = 0.f, w02 = 0.f, w03 = 0.f;
    float w10 = 0.f, w11 = 0.f, w12 = 0.f, w13 = 0.f, tsv = 0.f;
    if (AFFINE) {
        const float* wu = WU + b * 64 + o0;
        ad0 = wu[0]; ad1 = wu[1]; ad2 = wu[2]; ad3 = wu[3];
        w00 = Ww0[o0]; w01 = Ww0[o0 + 1]; w02 = Ww0[o0 + 2]; w03 = Ww0[o0 + 3];
        tsv = ts[t];
        w10 = Ww1[o0] * tsv; w11 = Ww1[o0 + 1] * tsv; w12 = Ww1[o0 + 2] * tsv; w13 = Ww1[o0 + 3] * tsv;
        ad0 += w10; ad1 += w11; ad2 += w12; ad3 += w13;
    } else {
        ad0 = bconv[o0]; ad1 = bconv[o0 + 1]; ad2 = bconv[o0 + 2]; ad3 = bconv[o0 + 3];
    }
#pragma unroll
    for (int nx = 0; nx < 8; ++nx) {
        int x = nx * 16 + ln;
        float xv = AFFINE ? xs[x] : 0.f;
        float v0 = acc[nx][0] + ad0;
        float v1 = acc[nx][1] + ad1;
        float v2 = acc[nx][2] + ad2;
        float v3 = acc[nx][3] + ad3;
        if (AFFINE) { v0 += xv * w00; v1 += xv * w01; v2 += xv * w02; v3 += xv * w03; }
        v0 = gelu_erf(v0); v1 = gelu_erf(v1); v2 = gelu_erf(v2); v3 = gelu_erf(v3);
        unsigned short hh[4], ll[4];
        split2(v0, hh[0], ll[0]); split2(v1, hh[1], ll[1]);
        split2(v2, hh[2], ll[2]); split2(v3, hh[3], ll[3]);
        size_t trow = btbase + (size_t)x * 64 + o0;
        *reinterpret_cast<uint2*>(&hTH[trow]) =
            make_uint2((unsigned)hh[0] | ((unsigned)hh[1] << 16), (unsigned)hh[2] | ((unsigned)hh[3] << 16));
        *reinterpret_cast<uint2*>(&hTL[trow]) =
            make_uint2((unsigned)ll[0] | ((unsigned)ll[1] << 16), (unsigned)ll[2] | ((unsigned)ll[3] << 16));
        hsf[o0 + 0][x] = v0; hsf[o0 + 1][x] = v1;
        hsf[o0 + 2][x] = v2; hsf[o0 + 3][x] = v3;
    }
    __syncthreads();
    // fused forward x-DFT of the new h
    int mw = w & 1, ng = (w >> 1) * 2;
    f32x4 acc2[2];
    acc2[0] = (f32x4){0.f, 0.f, 0.f, 0.f};
    acc2[1] = (f32x4){0.f, 0.f, 0.f, 0.f};
#pragma unroll
    for (int kt = 0; kt < 4; ++kt) {
        int aoff = (mw * 16 + ln) * 128 + kt * 32 + lg * 8;
        short8 aH = ld8(TfH + aoff);
        short8 aL = ld8(TfL + aoff);
#pragma unroll
        for (int j = 0; j < 2; ++j) {
            int c = (ng + j) * 16 + ln;
            float4 f0 = *reinterpret_cast<const float4*>(&hsf[c][kt * 32 + lg * 8]);
            float4 f1 = *reinterpret_cast<const float4*>(&hsf[c][kt * 32 + lg * 8 + 4]);
            short8 bH, bL;
            unsigned short h, l;
            split2(f0.x, h, l); bH[0] = (short)h; bL[0] = (short)l;
            split2(f0.y, h, l); bH[1] = (short)h; bL[1] = (short)l;
            split2(f0.z, h, l); bH[2] = (short)h; bL[2] = (short)l;
            split2(f0.w, h, l); bH[3] = (short)h; bL[3] = (short)l;
            split2(f1.x, h, l); bH[4] = (short)h; bL[4] = (short)l;
            split2(f1.y, h, l); bH[5] = (short)h; bL[5] = (short)l;
            split2(f1.z, h, l); bH[6] = (short)h; bL[6] = (short)l;
            split2(f1.w, h, l); bH[7] = (short)h; bL[7] = (short)l;
            MFMA3(acc2[j], aH, aL, bH, bL);
        }
    }
    __syncthreads();                    // hsf reads done; overlay A2 staging
    float* A2s = &hsf[0][0];            // [32][68]
#pragma unroll
    for (int j = 0; j < 2; ++j) {
        int c = (ng + j) * 16 + ln;
#pragma unroll
        for (int r = 0; r < 4; ++r) {
            int col = mw * 16 + lg * 4 + r;
            A2s[col * 68 + c] = acc2[j][r];
        }
    }
    __syncthreads();
    {
        int col = tid >> 3;
        if (col < 24) {
            int c0 = (tid & 7) * 8;
            unsigned short hh[8], ll[8];
#pragma unroll
            for (int j = 0; j < 8; ++j) split2(A2s[col * 68 + c0 + j], hh[j], ll[j]);
            size_t p = ((size_t)(b * 24 + col) * 128 + t) * 64 + c0;
            *reinterpret_cast<uint4*>(&A2H[p]) = make_uint4(
                (unsigned)hh[0] | ((unsigned)hh[1] << 16), (unsigned)hh[2] | ((unsigned)hh[3] << 16),
                (unsigned)hh[4] | ((unsigned)hh[5] << 16), (unsigned)hh[6] | ((unsigned)hh[7] << 16));
            *reinterpret_cast<uint4*>(&A2L[p]) = make_uint4(
                (unsigned)ll[0] | ((unsigned)ll[1] << 16), (unsigned)ll[2] | ((unsigned)ll[3] << 16),
                (unsigned)ll[4] | ((unsigned)ll[5] << 16), (unsigned)ll[6] | ((unsigned)ll[7] << 16));
        }
    }
}

// ---------------- conv layer 3 + head (fc1+gelu+fc2) fused ----------------
__global__ __launch_bounds__(256) void k_conv_head(const unsigned short* __restrict__ hTH, const unsigned short* __restrict__ hTL,
                                                   const unsigned short* __restrict__ WH, const unsigned short* __restrict__ WL,
                                                   const unsigned short* __restrict__ BvH, const unsigned short* __restrict__ BvL,
                                                   const unsigned short* __restrict__ TiXH, const unsigned short* __restrict__ TiXL,
                                                   const float* __restrict__ bconv,
                                                   const unsigned short* __restrict__ F1H, const unsigned short* __restrict__ F1L,
                                                   const float* __restrict__ b1, const float* __restrict__ w2,
                                                   const float* __restrict__ b2, float* __restrict__ out) {
    __shared__ float hsf[64][132];
    int bid = blockIdx.x, tid = threadIdx.x;
    int t = bid & 127, b = bid >> 7;
    int w = tid >> 6, lane = tid & 63, ln = lane & 15, lg = lane >> 4;
    size_t btbase = (size_t)(b * 128 + t) * 128 * 64;
    f32x4 acc[8];
#pragma unroll
    for (int nx = 0; nx < 8; ++nx) acc[nx] = (f32x4){0.f, 0.f, 0.f, 0.f};
#pragma unroll
    for (int kt = 0; kt < 2; ++kt) {
        int aoff = (w * 16 + ln) * 64 + kt * 32 + lg * 8;
        short8 aH = ld8(WH + aoff);
        short8 aL = ld8(WL + aoff);
#pragma unroll
        for (int nx = 0; nx < 8; ++nx) {
            size_t boff = btbase + (size_t)(nx * 16 + ln) * 64 + kt * 32 + lg * 8;
            short8 bH = ld8(hTH + boff);
            short8 bL = ld8(hTL + boff);
            MFMA3(acc[nx], aH, aL, bH, bL);
        }
    }
    {
        size_t aoff = ((size_t)(b * 64 + w * 16 + ln) * 128 + t) * 32 + lg * 8;
        short8 aH = ld8(BvH + aoff);
        short8 aL = ld8(BvL + aoff);
#pragma unroll
        for (int nx = 0; nx < 8; ++nx) {
            int boff = (nx * 16 + ln) * 32 + lg * 8;
            short8 bH = ld8(TiXH + boff);
            short8 bL = ld8(TiXL + boff);
            MFMA3(acc[nx], aH, aL, bH, bL);
        }
    }
    int o0 = w * 16 + lg * 4;
    float bc0 = bconv[o0], bc1 = bconv[o0 + 1], bc2 = bconv[o0 + 2], bc3 = bconv[o0 + 3];
#pragma unroll
    for (int nx = 0; nx < 8; ++nx) {
        int x = nx * 16 + ln;
        hsf[o0 + 0][x] = acc[nx][0] + bc0;
        hsf[o0 + 1][x] = acc[nx][1] + bc1;
        hsf[o0 + 2][x] = acc[nx][2] + bc2;
        hsf[o0 + 3][x] = acc[nx][3] + bc3;
    }
    __syncthreads();
    // head: z[d][x] = F1·h, gelu, out[x] = sum_d z*w2 + b2
    f32x4 acc2[2][8];
#pragma unroll
    for (int mi = 0; mi < 2; ++mi)
#pragma unroll
        for (int nx = 0; nx < 8; ++nx) acc2[mi][nx] = (f32x4){0.f, 0.f, 0.f, 0.f};
#pragma unroll
    for (int kc = 0; kc < 2; ++kc) {
        short8 bH[8], bL[8];
#pragma unroll
        for (int nx = 0; nx < 8; ++nx) {
            int x = nx * 16 + ln;
            int c0 = kc * 32 + lg * 8;
            unsigned short h, l;
#pragma unroll
            for (int j = 0; j < 8; ++j) {
                split2(hsf[c0 + j][x], h, l);
                bH[nx][j] = (short)h; bL[nx][j] = (short)l;
            }
        }
#pragma unroll
        for (int mi = 0; mi < 2; ++mi) {
            int aoff = ((w * 2 + mi) * 16 + ln) * 64 + kc * 32 + lg * 8;
            short8 aH = ld8(F1H + aoff);
            short8 aL = ld8(F1L + aoff);
#pragma unroll
            for (int nx = 0; nx < 8; ++nx) { MFMA3(acc2[mi][nx], aH, aL, bH[nx], bL[nx]); }
        }
    }
    float p[8] = {0.f, 0.f, 0.f, 0.f, 0.f, 0.f, 0.f, 0.f};
#pragma unroll
    for (int mi = 0; mi < 2; ++mi)
#pragma unroll
        for (int r = 0; r < 4; ++r) {
            int d = (w * 2 + mi) * 16 + lg * 4 + r;
            float bb = b1[d], wk = w2[d];
#pragma unroll
            for (int nx = 0; nx < 8; ++nx) {
                float v = acc2[mi][nx][r] + bb;
                p[nx] += gelu_erf(v) * wk;
            }
        }
    __syncthreads();                  // hsf reads done; overlay reduction buffer
    float* red = &hsf[0][0];          // [16][130]
#pragma unroll
    for (int nx = 0; nx < 8; ++nx) red[(w * 4 + lg) * 130 + nx * 16 + ln] = p[nx];
    __syncthreads();
    if (tid < 128) {
        float s = 0.f;
#pragma unroll
        for (int g = 0; g < 16; ++g) s += red[g * 130 + tid];
        out[((size_t)b * 128 + t) * 128 + tid] = s + b2[0];
    }
}

extern "C" void kernel_launch(void* const* d_in, const int* in_sizes, int n_in,
                              void* d_out, int out_size, void* d_ws, size_t ws_size,
                              hipStream_t stream) {
    const float* ts    = (const float*)d_in[0];
    const float* xs    = (const float*)d_in[1];
    const float* u0    = (const float*)d_in[2];
    const float* fc0_w = (const float*)d_in[3];
    const float* fc0_b = (const float*)d_in[4];
    const float* w1re  = (const float*)d_in[5];
    const float* w1im  = (const float*)d_in[6];
    const float* w2re  = (const float*)d_in[7];
    const float* w2im  = (const float*)d_in[8];
    const float* wconv = (const float*)d_in[9];
    const float* bconv = (const float*)d_in[10];
    const float* fc1w  = (const float*)d_in[11];
    const float* fc1b  = (const float*)d_in[12];
    const float* fc2w  = (const float*)d_in[13];
    const float* fc2b  = (const float*)d_in[14];
    float* out = (float*)d_out;

    char* ws = (char*)d_ws;
    size_t off = 0;
    auto alloc = [&](size_t bytes) -> char* {
        char* p = ws + off;
        off = (off + bytes + 255) & ~(size_t)255;
        return p;
    };
    unsigned short* hTH = (unsigned short*)alloc(33554432);   // [16*128*128][64]
    unsigned short* hTL = (unsigned short*)alloc(33554432);
    unsigned short* A2H = (unsigned short*)alloc(6291456);    // [16][24][128][64]
    unsigned short* A2L = (unsigned short*)alloc(6291456);
    float2* Hm = (float2*)alloc(2359296);                     // [288][16][64]
    float2* Om = (float2*)alloc(2359296);                     // [16][64][288]
    unsigned short* BvH = (unsigned short*)alloc(8388608);    // [16*64*128][32]
    unsigned short* BvL = (unsigned short*)alloc(8388608);
    float* U    = (float*)alloc(4096);
    float2* Sx  = (float2*)alloc(256);
    float2* St  = (float2*)alloc(256);
    float* Ww0  = (float*)alloc(256);
    float* Ww1  = (float*)alloc(256);
    float* WU   = (float*)alloc(4096);
    unsigned short* TfH  = (unsigned short*)alloc(8192);
    unsigned short* TfL  = (unsigned short*)alloc(8192);
    unsigned short* TiXH = (unsigned short*)alloc(8192);
    unsigned short* TiXL = (unsigned short*)alloc(8192);
    unsigned short* TDH  = (unsigned short*)alloc(24576);
    unsigned short* TDL  = (unsigned short*)alloc(24576);
    unsigned short* TIH  = (unsigned short*)alloc(16384);
    unsigned short* TIL  = (unsigned short*)alloc(16384);
    unsigned short* WH   = (unsigned short*)alloc(32768);
    unsigned short* WL   = (unsigned short*)alloc(32768);
    unsigned short* F1H  = (unsigned short*)alloc(16384);
    unsigned short* F1L  = (unsigned short*)alloc(16384);
    size_t base_need = off;
    if (ws_size < base_need) return;
    float2* Wt = (float2*)alloc(37748736);                    // [4][288][64][64]
    bool use_wt = (ws_size >= off);

    k_tables2<<<1, 256, 0, stream>>>(TfH, TfL, TiXH, TiXL, TDH, TDL, TIH, TIL);
    k_spec<<<1, 64, 0, stream>>>(xs, ts, Sx, St);
    k_u<<<16, 64, 0, stream>>>(u0, fc0_w, fc0_b, U);
    k_wprep<<<64, 256, 0, stream>>>(wconv, fc1w, WH, WL, F1H, F1L);
    k_cw<<<16, 64, 0, stream>>>(wconv, bconv, fc0_w, U, Ww0, Ww1, WU);
    k_hm0<<<288, 256, 0, stream>>>(fc0_w, U, Sx, St, Hm);
    if (use_wt)
        k_wt<<<512, 256, 0, stream>>>(w1re, w1im, w2re, w2im, Wt);

    for (int l = 0; l < 4; ++l) {
        if (l > 0)
            k_dftt2<<<192, 256, 0, stream>>>(A2H, A2L, TDH, TDL, Hm);
        if (use_wt)
            k_mix<<<576, 256, 0, stream>>>(Hm, Wt + (size_t)l * 288 * 4096, Om);
        else
            k_mix_raw<<<576, 256, 0, stream>>>(Hm, w1re + (size_t)l * 589824, w1im + (size_t)l * 589824,
                                               w2re + (size_t)l * 589824, w2im + (size_t)l * 589824, Om);
        k_idftt2<<<1024, 256, 0, stream>>>(Om, TIH, TIL, BvH, BvL);
        if (l == 0)
            k_conv_mid<1><<<2048, 256, 0, stream>>>(hTH, hTL, WH, WL, BvH, BvL, TiXH, TiXL,
                                                    TfH, TfL, A2H, A2L, bconv, xs, ts, Ww0, Ww1, WU);
        else if (l < 3)
            k_conv_mid<0><<<2048, 256, 0, stream>>>(hTH, hTL, WH + l * 4096, WL + l * 4096,
                                                    BvH, BvL, TiXH, TiXL, TfH, TfL, A2H, A2L,
                                                    bconv + l * 64, xs, ts, Ww0, Ww1, WU);
        else
            k_conv_head<<<2048, 256, 0, stream>>>(hTH, hTL, WH + 3 * 4096, WL + 3 * 4096,
                                                  BvH, BvL, TiXH, TiXL, bconv + 3 * 64,
                                                  F1H, F1L, fc1b, fc2w, fc2b, out);
    }
}

// Round 8
// 580.411 us; speedup vs baseline: 1.3468x; 1.0521x over previous
//
#include <hip/hip_runtime.h>
#include <math.h>

// FNO: N=16, H=64, NT=128, NX=128, M=12, DH=128, DIN=128
// R7 (resubmit after broker timeout): state = hT[b,t,x][c] split-bf16 (hi/lo).
// Layer-0 fully analytic. Head fused into conv layer 3. Conv epilogues write
// split-bf16 LDS planes once; downstream MFMA phases read fragments directly.

typedef __attribute__((ext_vector_type(8))) short short8;
typedef __attribute__((ext_vector_type(4))) float f32x4;

__device__ inline unsigned short bf16rn(float v) {
    unsigned int b = __float_as_uint(v);
    return (unsigned short)((b + 0x7FFFu + ((b >> 16) & 1u)) >> 16);
}
__device__ inline void split2(float v, unsigned short& h, unsigned short& l) {
    h = bf16rn(v);
    float hf = __uint_as_float((unsigned int)h << 16);
    l = bf16rn(v - hf);
}
__device__ inline short8 ld8(const unsigned short* p) {
    return *reinterpret_cast<const short8*>(p);
}
__device__ inline float gelu_erf(float v) {
    return 0.5f * v * (1.0f + erff(v * 0.70710678118654752f));
}
#define MFMA3(accv, aH, aL, bH, bL) \
    accv = __builtin_amdgcn_mfma_f32_16x16x32_bf16(aH, bH, accv, 0, 0, 0); \
    accv = __builtin_amdgcn_mfma_f32_16x16x32_bf16(aH, bL, accv, 0, 0, 0); \
    accv = __builtin_amdgcn_mfma_f32_16x16x32_bf16(aL, bH, accv, 0, 0, 0);

#define STEPC 0.049087385212340519350f  // 2*pi/128

// ---------------- tables ----------------
__global__ __launch_bounds__(256) void k_tables2(unsigned short* TfH, unsigned short* TfL,
                                                 unsigned short* TiXH, unsigned short* TiXL,
                                                 unsigned short* TDH, unsigned short* TDL,
                                                 unsigned short* TIH, unsigned short* TIL) {
    int tid = threadIdx.x;
    unsigned short h, l;
    for (int i = tid; i < 32 * 128; i += 256) {
        int row = i >> 7, x = i & 127;
        float v = 0.f;
        if (row < 24) {
            int kx = row >> 1;
            float th = ((kx * x) & 127) * STEPC;
            v = (row & 1) ? -sinf(th) : cosf(th);
        }
        split2(v, h, l); TfH[i] = h; TfL[i] = l;
    }
    for (int i = tid; i < 128 * 32; i += 256) {
        int x = i >> 5, col = i & 31;
        float v = 0.f;
        if (col < 24) {
            int kx = col >> 1;
            float th = ((kx * x) & 127) * STEPC;
            float w = (kx == 0 ? 1.0f : 2.0f) / 16384.0f;
            v = (col & 1) ? -w * sinf(th) : w * cosf(th);
        }
        split2(v, h, l); TiXH[i] = h; TiXL[i] = l;
    }
    for (int i = tid; i < 2 * 48 * 128; i += 256) {
        int q = i >> 12;
        int rem = i & 6143;
        int row = rem >> 7, t = rem & 127;
        int kt = row >> 1;
        int f = (kt < 12) ? kt : (kt + 104);
        float th = ((f * t) & 127) * STEPC;
        float c = cosf(th), s = sinf(th);
        float v;
        if (q == 0) v = (row & 1) ? -s : c;
        else        v = (row & 1) ?  c : s;
        split2(v, h, l); TDH[i] = h; TDL[i] = l;
    }
    for (int i = tid; i < 128 * 64; i += 256) {
        int t = i >> 6, col = i & 63;
        float v = 0.f;
        if (col < 48) {
            int kt = col >> 1;
            int f = (kt < 12) ? kt : (kt + 104);
            float th = ((f * t) & 127) * STEPC;
            v = (col & 1) ? -sinf(th) : cosf(th);
        }
        split2(v, h, l); TIH[i] = h; TIL[i] = l;
    }
}

__global__ void k_spec(const float* __restrict__ xs, const float* __restrict__ ts,
                       float2* __restrict__ Sx, float2* __restrict__ St) {
    int tid = threadIdx.x;
    if (tid < 12) {
        float re = 0.f, im = 0.f;
        for (int x = 0; x < 128; ++x) {
            float th = ((tid * x) & 127) * STEPC;
            re += xs[x] * cosf(th); im -= xs[x] * sinf(th);
        }
        Sx[tid] = make_float2(re, im);
    } else if (tid >= 32 && tid < 56) {
        int kt = tid - 32;
        int f = (kt < 12) ? kt : (kt + 104);
        float re = 0.f, im = 0.f;
        for (int t = 0; t < 128; ++t) {
            float th = ((f * t) & 127) * STEPC;
            re += ts[t] * cosf(th); im -= ts[t] * sinf(th);
        }
        St[kt] = make_float2(re, im);
    }
}

__global__ void k_u(const float* __restrict__ u0, const float* __restrict__ w,
                    const float* __restrict__ bias, float* __restrict__ U) {
    int b = blockIdx.x, c = threadIdx.x;
    float acc = bias[c];
    const float* wr = w + c * 130 + 2;
    const float* ur = u0 + b * 128;
    for (int d = 0; d < 128; ++d) acc += ur[d] * wr[d];
    U[b * 64 + c] = acc;
}

__global__ __launch_bounds__(256) void k_wprep(const float* __restrict__ wconv, const float* __restrict__ fc1w,
                                               unsigned short* WH, unsigned short* WL,
                                               unsigned short* F1H, unsigned short* F1L) {
    int i = blockIdx.x * 256 + threadIdx.x;
    if (i < 16384) split2(wconv[i], WH[i], WL[i]);
    if (i < 8192)  split2(fc1w[i], F1H[i], F1L[i]);
}

__global__ void k_cw(const float* __restrict__ wconv, const float* __restrict__ bconv,
                     const float* __restrict__ fc0_w, const float* __restrict__ U,
                     float* __restrict__ Ww0, float* __restrict__ Ww1, float* __restrict__ WU) {
    int b = blockIdx.x, o = threadIdx.x;
    const float* wr = wconv + o * 64;
    float au = bconv[o];
    const float* ur = U + b * 64;
    for (int c = 0; c < 64; ++c) au += wr[c] * ur[c];
    WU[b * 64 + o] = au;
    if (b == 0) {
        float a0 = 0.f, a1 = 0.f;
        for (int c = 0; c < 64; ++c) {
            a0 += wr[c] * fc0_w[c * 130];
            a1 += wr[c] * fc0_w[c * 130 + 1];
        }
        Ww0[o] = a0; Ww1[o] = a1;
    }
}

__global__ __launch_bounds__(256) void k_hm0(const float* __restrict__ fc0_w, const float* __restrict__ U,
                                             const float2* __restrict__ Sx, const float2* __restrict__ St,
                                             float2* __restrict__ Hm) {
    __shared__ float w0s[64], w1s[64];
    int mode = blockIdx.x, tid = threadIdx.x;
    int kt = mode / 12, kx = mode - kt * 12;
    if (tid < 64) { w0s[tid] = fc0_w[tid * 130]; w1s[tid] = fc0_w[tid * 130 + 1]; }
    __syncthreads();
    float2 sx = Sx[kx], st = St[kt];
    for (int i = tid; i < 1024; i += 256) {
        int b = i >> 6, c = i & 63;
        float re = 0.f, im = 0.f;
        if (kt == 0) { re += 128.f * w0s[c] * sx.x; im += 128.f * w0s[c] * sx.y; }
        if (kx == 0) { re += 128.f * w1s[c] * st.x; im += 128.f * w1s[c] * st.y; }
        if (kt == 0 && kx == 0) re += 16384.f * U[b * 64 + c];
        Hm[((size_t)mode * 16 + b) * 64 + c] = make_float2(re, im);
    }
}

__global__ __launch_bounds__(256) void k_wt(const float* __restrict__ w1re, const float* __restrict__ w1im,
                                            const float* __restrict__ w2re, const float* __restrict__ w2im,
                                            float2* __restrict__ Wt) {
    __shared__ float ldsre[32 * 145];
    __shared__ float ldsim[32 * 145];
    int bid = blockIdx.x, tid = threadIdx.x;
    int c = bid & 63, tbl = (bid >> 6) & 1, l = bid >> 7;
    const float* re = (tbl ? w2re : w1re) + (size_t)((l * 64 + c) * 64) * 144;
    const float* im = (tbl ? w2im : w1im) + (size_t)((l * 64 + c) * 64) * 144;
    int moff = tbl * 144;
    for (int half = 0; half < 2; ++half) {
        __syncthreads();
        for (int i = tid; i < 32 * 144; i += 256) {
            int o = i / 144, m = i - o * 144;
            ldsre[o * 145 + m] = re[(half * 32 + o) * 144 + m];
            ldsim[o * 145 + m] = im[(half * 32 + o) * 144 + m];
        }
        __syncthreads();
        for (int i = tid; i < 32 * 144; i += 256) {
            int mode = i >> 5, o = i & 31;
            Wt[((size_t)(l * 288 + moff + mode) * 64 + c) * 64 + half * 32 + o] =
                make_float2(ldsre[o * 145 + mode], ldsim[o * 145 + mode]);
        }
    }
}

// ---------------- forward t-DFT ----------------
__global__ __launch_bounds__(256) void k_dftt2(const unsigned short* __restrict__ A2H, const unsigned short* __restrict__ A2L,
                                               const unsigned short* __restrict__ TDH, const unsigned short* __restrict__ TDL,
                                               float2* __restrict__ Hm) {
    __shared__ unsigned short sH[64][136], sL[64][136];
    int bid = blockIdx.x, tid = threadIdx.x;
    int b = bid / 12, kx = bid - b * 12;
    int w = tid >> 6, lane = tid & 63, ln = lane & 15, lg = lane >> 4;
    f32x4 acc[3];
#pragma unroll
    for (int m = 0; m < 3; ++m) acc[m] = (f32x4){0.f, 0.f, 0.f, 0.f};
#pragma unroll
    for (int q = 0; q < 2; ++q) {
        if (q) __syncthreads();
        int col = 2 * kx + q;
        const unsigned short* srcH = A2H + (size_t)(b * 24 + col) * 128 * 64;
        const unsigned short* srcL = A2L + (size_t)(b * 24 + col) * 128 * 64;
        for (int i = tid; i < 1024; i += 256) {
            int t = i >> 3, c0 = (i & 7) * 8;
            uint4 vh = *reinterpret_cast<const uint4*>(srcH + t * 64 + c0);
            uint4 vl = *reinterpret_cast<const uint4*>(srcL + t * 64 + c0);
            const unsigned short* ph = (const unsigned short*)&vh;
            const unsigned short* pl = (const unsigned short*)&vl;
#pragma unroll
            for (int j = 0; j < 8; ++j) {
                sH[c0 + j][t] = ph[j];
                sL[c0 + j][t] = pl[j];
            }
        }
        __syncthreads();
#pragma unroll
        for (int ks = 0; ks < 4; ++ks) {
            short8 bH = ld8(&sH[w * 16 + ln][ks * 32 + lg * 8]);
            short8 bL = ld8(&sL[w * 16 + ln][ks * 32 + lg * 8]);
#pragma unroll
            for (int m = 0; m < 3; ++m) {
                int aoff = (q * 48 + m * 16 + ln) * 128 + ks * 32 + lg * 8;
                short8 aH = ld8(TDH + aoff);
                short8 aL = ld8(TDL + aoff);
                MFMA3(acc[m], aH, aL, bH, bL);
            }
        }
    }
    float* Hf = (float*)Hm;
    int c = w * 16 + ln;
#pragma unroll
    for (int m = 0; m < 3; ++m)
#pragma unroll
        for (int r = 0; r < 4; ++r) {
            int row = m * 16 + lg * 4 + r;
            int kt = row >> 1, pp = row & 1;
            Hf[(((size_t)(kt * 12 + kx) * 16 + b) * 64 + c) * 2 + pp] = acc[m][r];
        }
}

// ---------------- per-mode channel mix (fp32) ----------------
__global__ __launch_bounds__(256) void k_mix(const float2* __restrict__ Hm, const float2* __restrict__ WtL,
                                             float2* __restrict__ Om) {
    __shared__ float2 hl[8 * 64];
    int bid = blockIdx.x, tid = threadIdx.x;
    int mode = bid >> 1, bh = bid & 1;
    const float2* hsrc = Hm + ((size_t)mode * 16 + bh * 8) * 64;
    for (int i = tid; i < 512; i += 256) hl[i] = hsrc[i];
    __syncthreads();
    int o = tid & 63, bg = tid >> 6;
    const float2* wp = WtL + (size_t)mode * 4096 + o;
    const float2* h0 = hl + (bg * 2) * 64;
    const float2* h1 = hl + (bg * 2 + 1) * 64;
    float a0r = 0.f, a0i = 0.f, a1r = 0.f, a1i = 0.f;
#pragma unroll 4
    for (int c = 0; c < 64; ++c) {
        float2 wv = wp[c * 64];
        float2 a0 = h0[c], a1 = h1[c];
        a0r += a0.x * wv.x - a0.y * wv.y;
        a0i += a0.x * wv.y + a0.y * wv.x;
        a1r += a1.x * wv.x - a1.y * wv.y;
        a1i += a1.x * wv.y + a1.y * wv.x;
    }
    int b0 = bh * 8 + bg * 2;
    Om[((size_t)(b0)*64 + o) * 288 + mode]       = make_float2(a0r, a0i);
    Om[((size_t)(b0 + 1) * 64 + o) * 288 + mode] = make_float2(a1r, a1i);
}

__global__ __launch_bounds__(256) void k_mix_raw(const float2* __restrict__ Hm,
                                                 const float* __restrict__ w1re, const float* __restrict__ w1im,
                                                 const float* __restrict__ w2re, const float* __restrict__ w2im,
                                                 float2* __restrict__ Om) {
    __shared__ float2 hl[8 * 64];
    int bid = blockIdx.x, tid = threadIdx.x;
    int mode = bid >> 1, bh = bid & 1;
    const float2* hsrc = Hm + ((size_t)mode * 16 + bh * 8) * 64;
    for (int i = tid; i < 512; i += 256) hl[i] = hsrc[i];
    __syncthreads();
    int kti = mode / 12, kx = mode - kti * 12;
    const float* re; const float* im; int ktw;
    if (kti < 12) { re = w1re; im = w1im; ktw = kti; }
    else          { re = w2re; im = w2im; ktw = kti - 12; }
    int off = ktw * 12 + kx;
    int o = tid & 63, bg = tid >> 6;
    const float2* h0 = hl + (bg * 2) * 64;
    const float2* h1 = hl + (bg * 2 + 1) * 64;
    float a0r = 0.f, a0i = 0.f, a1r = 0.f, a1i = 0.f;
    for (int c = 0; c < 64; ++c) {
        size_t widx = (size_t)(c * 64 + o) * 144 + off;
        float wr = re[widx], wi = im[widx];
        float2 a0 = h0[c], a1 = h1[c];
        a0r += a0.x * wr - a0.y * wi;
        a0i += a0.x * wi + a0.y * wr;
        a1r += a1.x * wr - a1.y * wi;
        a1i += a1.x * wi + a1.y * wr;
    }
    int b0 = bh * 8 + bg * 2;
    Om[((size_t)(b0)*64 + o) * 288 + mode]       = make_float2(a0r, a0i);
    Om[((size_t)(b0 + 1) * 64 + o) * 288 + mode] = make_float2(a1r, a1i);
}

// ---------------- inverse t-DFT ----------------
__global__ __launch_bounds__(256) void k_idftt2(const float2* __restrict__ Om,
                                                const unsigned short* __restrict__ TIH, const unsigned short* __restrict__ TIL,
                                                unsigned short* __restrict__ BvH, unsigned short* __restrict__ BvL) {
    __shared__ unsigned short OmH[32][72], OmL[32][72];
    int bo = blockIdx.x, tid = threadIdx.x;
    unsigned int* zh = (unsigned int*)&OmH[0][0];
    unsigned int* zl = (unsigned int*)&OmL[0][0];
    for (int i = tid; i < 1152; i += 256) { zh[i] = 0u; zl[i] = 0u; }
    __syncthreads();
    const float2* src = Om + (size_t)bo * 288;
    for (int i = tid; i < 288; i += 256) {
        int kt = i / 12, kx = i - kt * 12;
        float2 o = src[i];
        unsigned short h, l;
        split2(o.x, h, l);  OmH[2 * kx][2 * kt] = h;     OmL[2 * kx][2 * kt] = l;
        split2(o.y, h, l);  OmH[2 * kx][2 * kt + 1] = h; OmL[2 * kx][2 * kt + 1] = l;
                            OmH[2 * kx + 1][2 * kt] = h; OmL[2 * kx + 1][2 * kt] = l;
        split2(-o.x, h, l); OmH[2 * kx + 1][2 * kt + 1] = h; OmL[2 * kx + 1][2 * kt + 1] = l;
    }
    __syncthreads();
    int w = tid >> 6, lane = tid & 63, ln = lane & 15, lg = lane >> 4;
    f32x4 acc[2][2];
#pragma unroll
    for (int mi = 0; mi < 2; ++mi)
#pragma unroll
        for (int nt = 0; nt < 2; ++nt) acc[mi][nt] = (f32x4){0.f, 0.f, 0.f, 0.f};
#pragma unroll
    for (int ks = 0; ks < 2; ++ks) {
        short8 bH[2], bL[2];
#pragma unroll
        for (int nt = 0; nt < 2; ++nt) {
            int boff = (nt * 16 + ln) * 72 + ks * 32 + lg * 8;
            bH[nt] = ld8(&OmH[0][0] + boff);
            bL[nt] = ld8(&OmL[0][0] + boff);
        }
#pragma unroll
        for (int mi = 0; mi < 2; ++mi) {
            int aoff = ((w * 2 + mi) * 16 + ln) * 64 + ks * 32 + lg * 8;
            short8 aH = ld8(TIH + aoff);
            short8 aL = ld8(TIL + aoff);
#pragma unroll
            for (int nt = 0; nt < 2; ++nt) { MFMA3(acc[mi][nt], aH, aL, bH[nt], bL[nt]); }
        }
    }
#pragma unroll
    for (int mi = 0; mi < 2; ++mi)
#pragma unroll
        for (int nt = 0; nt < 2; ++nt)
#pragma unroll
            for (int r = 0; r < 4; ++r) {
                int trow = (w * 2 + mi) * 16 + lg * 4 + r;
                int col = nt * 16 + ln;
                unsigned short h, l;
                split2(acc[mi][nt][r], h, l);
                size_t p = ((size_t)bo * 128 + trow) * 32 + col;
                BvH[p] = h; BvL[p] = l;
            }
}

// ---------------- conv (mid / layer0) + inv x-DFT + gelu + fused fwd x-DFT ----------------
// Epilogue writes split-bf16 planes pH/pL[c][x]; fused x-DFT reads fragments directly.
template <int AFFINE>
__global__ __launch_bounds__(256) void k_conv_mid(unsigned short* __restrict__ hTH, unsigned short* __restrict__ hTL,
                                                  const unsigned short* __restrict__ WH, const unsigned short* __restrict__ WL,
                                                  const unsigned short* __restrict__ BvH, const unsigned short* __restrict__ BvL,
                                                  const unsigned short* __restrict__ TiXH, const unsigned short* __restrict__ TiXL,
                                                  const unsigned short* __restrict__ TfH, const unsigned short* __restrict__ TfL,
                                                  unsigned short* __restrict__ A2H, unsigned short* __restrict__ A2L,
                                                  const float* __restrict__ bconv,
                                                  const float* __restrict__ xs, const float* __restrict__ ts,
                                                  const float* __restrict__ Ww0, const float* __restrict__ Ww1,
                                                  const float* __restrict__ WU) {
    __shared__ unsigned short pH[64][136], pL[64][136];
    int bid = blockIdx.x, tid = threadIdx.x;
    int t = bid & 127, b = bid >> 7;
    int w = tid >> 6, lane = tid & 63, ln = lane & 15, lg = lane >> 4;
    size_t btbase = (size_t)(b * 128 + t) * 128 * 64;
    f32x4 acc[8];
#pragma unroll
    for (int nx = 0; nx < 8; ++nx) acc[nx] = (f32x4){0.f, 0.f, 0.f, 0.f};
    if (!AFFINE) {
#pragma unroll
        for (int kt = 0; kt < 2; ++kt) {
            int aoff = (w * 16 + ln) * 64 + kt * 32 + lg * 8;
            short8 aH = ld8(WH + aoff);
            short8 aL = ld8(WL + aoff);
#pragma unroll
            for (int nx = 0; nx < 8; ++nx) {
                size_t boff = btbase + (size_t)(nx * 16 + ln) * 64 + kt * 32 + lg * 8;
                short8 bH = ld8(hTH + boff);
                short8 bL = ld8(hTL + boff);
                MFMA3(acc[nx], aH, aL, bH, bL);
            }
        }
    }
    {
        size_t aoff = ((size_t)(b * 64 + w * 16 + ln) * 128 + t) * 32 + lg * 8;
        short8 aH = ld8(BvH + aoff);
        short8 aL = ld8(BvL + aoff);
#pragma unroll
        for (int nx = 0; nx < 8; ++nx) {
            int boff = (nx * 16 + ln) * 32 + lg * 8;
            short8 bH = ld8(TiXH + boff);
            short8 bL = ld8(TiXL + boff);
            MFMA3(acc[nx], aH, aL, bH, bL);
        }
    }
    __syncthreads();   // hT reads complete before in-place update
    int o0 = w * 16 + lg * 4;
    float ad0, ad1, ad2, ad3, w00 = 0.f, w01 = 0.f, w02 = 0.f, w03 = 0.f;
    if (AFFINE) {
        const float* wu = WU + b * 64 + o0;
        float tsv = ts[t];
        ad0 = wu[0] + Ww1[o0] * tsv;     ad1 = wu[1] + Ww1[o0 + 1] * tsv;
        ad2 = wu[2] + Ww1[o0 + 2] * tsv; ad3 = wu[3] + Ww1[o0 + 3] * tsv;
        w00 = Ww0[o0]; w01 = Ww0[o0 + 1]; w02 = Ww0[o0 + 2]; w03 = Ww0[o0 + 3];
    } else {
        ad0 = bconv[o0]; ad1 = bconv[o0 + 1]; ad2 = bconv[o0 + 2]; ad3 = bconv[o0 + 3];
    }
#pragma unroll
    for (int nx = 0; nx < 8; ++nx) {
        int x = nx * 16 + ln;
        float xv = AFFINE ? xs[x] : 0.f;
        float v0 = acc[nx][0] + ad0;
        float v1 = acc[nx][1] + ad1;
        float v2 = acc[nx][2] + ad2;
        float v3 = acc[nx][3] + ad3;
        if (AFFINE) { v0 += xv * w00; v1 += xv * w01; v2 += xv * w02; v3 += xv * w03; }
        v0 = gelu_erf(v0); v1 = gelu_erf(v1); v2 = gelu_erf(v2); v3 = gelu_erf(v3);
        unsigned short hh[4], ll[4];
        split2(v0, hh[0], ll[0]); split2(v1, hh[1], ll[1]);
        split2(v2, hh[2], ll[2]); split2(v3, hh[3], ll[3]);
        size_t trow = btbase + (size_t)x * 64 + o0;
        *reinterpret_cast<uint2*>(&hTH[trow]) =
            make_uint2((unsigned)hh[0] | ((unsigned)hh[1] << 16), (unsigned)hh[2] | ((unsigned)hh[3] << 16));
        *reinterpret_cast<uint2*>(&hTL[trow]) =
            make_uint2((unsigned)ll[0] | ((unsigned)ll[1] << 16), (unsigned)ll[2] | ((unsigned)ll[3] << 16));
        pH[o0 + 0][x] = hh[0]; pL[o0 + 0][x] = ll[0];
        pH[o0 + 1][x] = hh[1]; pL[o0 + 1][x] = ll[1];
        pH[o0 + 2][x] = hh[2]; pL[o0 + 2][x] = ll[2];
        pH[o0 + 3][x] = hh[3]; pL[o0 + 3][x] = ll[3];
    }
    __syncthreads();
    // fused forward x-DFT of the new h (B-frags: direct ld8 from pH/pL rows)
    int mw = w & 1, ng = (w >> 1) * 2;
    f32x4 acc2[2];
    acc2[0] = (f32x4){0.f, 0.f, 0.f, 0.f};
    acc2[1] = (f32x4){0.f, 0.f, 0.f, 0.f};
#pragma unroll
    for (int kt = 0; kt < 4; ++kt) {
        int aoff = (mw * 16 + ln) * 128 + kt * 32 + lg * 8;
        short8 aH = ld8(TfH + aoff);
        short8 aL = ld8(TfL + aoff);
#pragma unroll
        for (int j = 0; j < 2; ++j) {
            int c = (ng + j) * 16 + ln;
            short8 bH = ld8(&pH[c][kt * 32 + lg * 8]);
            short8 bL = ld8(&pL[c][kt * 32 + lg * 8]);
            MFMA3(acc2[j], aH, aL, bH, bL);
        }
    }
    __syncthreads();                    // pH/pL reads done; overlay A2 staging
    float* A2s = (float*)&pH[0][0];     // [32][68] f32, fits in pH region
#pragma unroll
    for (int j = 0; j < 2; ++j) {
        int c = (ng + j) * 16 + ln;
#pragma unroll
        for (int r = 0; r < 4; ++r) {
            int col = mw * 16 + lg * 4 + r;
            A2s[col * 68 + c] = acc2[j][r];
        }
    }
    __syncthreads();
    {
        int col = tid >> 3;
        if (col < 24) {
            int c0 = (tid & 7) * 8;
            unsigned short hh[8], ll[8];
#pragma unroll
            for (int j = 0; j < 8; ++j) split2(A2s[col * 68 + c0 + j], hh[j], ll[j]);
            size_t p = ((size_t)(b * 24 + col) * 128 + t) * 64 + c0;
            *reinterpret_cast<uint4*>(&A2H[p]) = make_uint4(
                (unsigned)hh[0] | ((unsigned)hh[1] << 16), (unsigned)hh[2] | ((unsigned)hh[3] << 16),
                (unsigned)hh[4] | ((unsigned)hh[5] << 16), (unsigned)hh[6] | ((unsigned)hh[7] << 16));
            *reinterpret_cast<uint4*>(&A2L[p]) = make_uint4(
                (unsigned)ll[0] | ((unsigned)ll[1] << 16), (unsigned)ll[2] | ((unsigned)ll[3] << 16),
                (unsigned)ll[4] | ((unsigned)ll[5] << 16), (unsigned)ll[6] | ((unsigned)ll[7] << 16));
        }
    }
}

// ---------------- conv layer 3 + head (fc1+gelu+fc2) fused ----------------
// conv output stored split-bf16 in pH/pL[x][c]; head B-frags are direct ld8 row reads.
__global__ __launch_bounds__(256) void k_conv_head(const unsigned short* __restrict__ hTH, const unsigned short* __restrict__ hTL,
                                                   const unsigned short* __restrict__ WH, const unsigned short* __restrict__ WL,
                                                   const unsigned short* __restrict__ BvH, const unsigned short* __restrict__ BvL,
                                                   const unsigned short* __restrict__ TiXH, const unsigned short* __restrict__ TiXL,
                                                   const float* __restrict__ bconv,
                                                   const unsigned short* __restrict__ F1H, const unsigned short* __restrict__ F1L,
                                                   const float* __restrict__ b1, const float* __restrict__ w2,
                                                   const float* __restrict__ b2, float* __restrict__ out) {
    __shared__ unsigned short pH[128][72], pL[128][72];
    int bid = blockIdx.x, tid = threadIdx.x;
    int t = bid & 127, b = bid >> 7;
    int w = tid >> 6, lane = tid & 63, ln = lane & 15, lg = lane >> 4;
    size_t btbase = (size_t)(b * 128 + t) * 128 * 64;
    {
        f32x4 acc[8];
#pragma unroll
        for (int nx = 0; nx < 8; ++nx) acc[nx] = (f32x4){0.f, 0.f, 0.f, 0.f};
#pragma unroll
        for (int kt = 0; kt < 2; ++kt) {
            int aoff = (w * 16 + ln) * 64 + kt * 32 + lg * 8;
            short8 aH = ld8(WH + aoff);
            short8 aL = ld8(WL + aoff);
#pragma unroll
            for (int nx = 0; nx < 8; ++nx) {
                size_t boff = btbase + (size_t)(nx * 16 + ln) * 64 + kt * 32 + lg * 8;
                short8 bH = ld8(hTH + boff);
                short8 bL = ld8(hTL + boff);
                MFMA3(acc[nx], aH, aL, bH, bL);
            }
        }
        {
            size_t aoff = ((size_t)(b * 64 + w * 16 + ln) * 128 + t) * 32 + lg * 8;
            short8 aH = ld8(BvH + aoff);
            short8 aL = ld8(BvL + aoff);
#pragma unroll
            for (int nx = 0; nx < 8; ++nx) {
                int boff = (nx * 16 + ln) * 32 + lg * 8;
                short8 bH = ld8(TiXH + boff);
                short8 bL = ld8(TiXL + boff);
                MFMA3(acc[nx], aH, aL, bH, bL);
            }
        }
        int o0 = w * 16 + lg * 4;
        float bc0 = bconv[o0], bc1 = bconv[o0 + 1], bc2 = bconv[o0 + 2], bc3 = bconv[o0 + 3];
#pragma unroll
        for (int nx = 0; nx < 8; ++nx) {
            int x = nx * 16 + ln;
            unsigned short hh[4], ll[4];
            split2(acc[nx][0] + bc0, hh[0], ll[0]);
            split2(acc[nx][1] + bc1, hh[1], ll[1]);
            split2(acc[nx][2] + bc2, hh[2], ll[2]);
            split2(acc[nx][3] + bc3, hh[3], ll[3]);
            *reinterpret_cast<uint2*>(&pH[x][o0]) =
                make_uint2((unsigned)hh[0] | ((unsigned)hh[1] << 16), (unsigned)hh[2] | ((unsigned)hh[3] << 16));
            *reinterpret_cast<uint2*>(&pL[x][o0]) =
                make_uint2((unsigned)ll[0] | ((unsigned)ll[1] << 16), (unsigned)ll[2] | ((unsigned)ll[3] << 16));
        }
    }
    __syncthreads();
    // head: z[d][x] = F1·h3, gelu, out[x] = sum_d z*w2 + b2. Two mi passes (VGPR).
    float p[8] = {0.f, 0.f, 0.f, 0.f, 0.f, 0.f, 0.f, 0.f};
#pragma unroll
    for (int mi = 0; mi < 2; ++mi) {
        f32x4 acc2[8];
#pragma unroll
        for (int nx = 0; nx < 8; ++nx) acc2[nx] = (f32x4){0.f, 0.f, 0.f, 0.f};
#pragma unroll
        for (int kc = 0; kc < 2; ++kc) {
            int aoff = ((w * 2 + mi) * 16 + ln) * 64 + kc * 32 + lg * 8;
            short8 aH = ld8(F1H + aoff);
            short8 aL = ld8(F1L + aoff);
#pragma unroll
            for (int nx = 0; nx < 8; ++nx) {
                int x = nx * 16 + ln;
                short8 bH = ld8(&pH[x][kc * 32 + lg * 8]);
                short8 bL = ld8(&pL[x][kc * 32 + lg * 8]);
                MFMA3(acc2[nx], aH, aL, bH, bL);
            }
        }
#pragma unroll
        for (int r = 0; r < 4; ++r) {
            int d = (w * 2 + mi) * 16 + lg * 4 + r;
            float bb = b1[d], wk = w2[d];
#pragma unroll
            for (int nx = 0; nx < 8; ++nx) {
                float v = acc2[nx][r] + bb;
                p[nx] += gelu_erf(v) * wk;
            }
        }
    }
    __syncthreads();                  // pH reads done; overlay reduction buffer
    float* red = (float*)&pH[0][0];   // [16][130]
#pragma unroll
    for (int nx = 0; nx < 8; ++nx) red[(w * 4 + lg) * 130 + nx * 16 + ln] = p[nx];
    __syncthreads();
    if (tid < 128) {
        float s = 0.f;
#pragma unroll
        for (int g = 0; g < 16; ++g) s += red[g * 130 + tid];
        out[((size_t)b * 128 + t) * 128 + tid] = s + b2[0];
    }
}

extern "C" void kernel_launch(void* const* d_in, const int* in_sizes, int n_in,
                              void* d_out, int out_size, void* d_ws, size_t ws_size,
                              hipStream_t stream) {
    const float* ts    = (const float*)d_in[0];
    const float* xs    = (const float*)d_in[1];
    const float* u0    = (const float*)d_in[2];
    const float* fc0_w = (const float*)d_in[3];
    const float* fc0_b = (const float*)d_in[4];
    const float* w1re  = (const float*)d_in[5];
    const float* w1im  = (const float*)d_in[6];
    const float* w2re  = (const float*)d_in[7];
    const float* w2im  = (const float*)d_in[8];
    const float* wconv = (const float*)d_in[9];
    const float* bconv = (const float*)d_in[10];
    const float* fc1w  = (const float*)d_in[11];
    const float* fc1b  = (const float*)d_in[12];
    const float* fc2w  = (const float*)d_in[13];
    const float* fc2b  = (const float*)d_in[14];
    float* out = (float*)d_out;

    char* ws = (char*)d_ws;
    size_t off = 0;
    auto alloc = [&](size_t bytes) -> char* {
        char* p = ws + off;
        off = (off + bytes + 255) & ~(size_t)255;
        return p;
    };
    unsigned short* hTH = (unsigned short*)alloc(33554432);   // [16*128*128][64]
    unsigned short* hTL = (unsigned short*)alloc(33554432);
    unsigned short* A2H = (unsigned short*)alloc(6291456);    // [16][24][128][64]
    unsigned short* A2L = (unsigned short*)alloc(6291456);
    float2* Hm = (float2*)alloc(2359296);                     // [288][16][64]
    float2* Om = (float2*)alloc(2359296);                     // [16][64][288]
    unsigned short* BvH = (unsigned short*)alloc(8388608);    // [16*64*128][32]
    unsigned short* BvL = (unsigned short*)alloc(8388608);
    float* U    = (float*)alloc(4096);
    float2* Sx  = (float2*)alloc(256);
    float2* St  = (float2*)alloc(256);
    float* Ww0  = (float*)alloc(256);
    float* Ww1  = (float*)alloc(256);
    float* WU   = (float*)alloc(4096);
    unsigned short* TfH  = (unsigned short*)alloc(8192);
    unsigned short* TfL  = (unsigned short*)alloc(8192);
    unsigned short* TiXH = (unsigned short*)alloc(8192);
    unsigned short* TiXL = (unsigned short*)alloc(8192);
    unsigned short* TDH  = (unsigned short*)alloc(24576);
    unsigned short* TDL  = (unsigned short*)alloc(24576);
    unsigned short* TIH  = (unsigned short*)alloc(16384);
    unsigned short* TIL  = (unsigned short*)alloc(16384);
    unsigned short* WH   = (unsigned short*)alloc(32768);
    unsigned short* WL   = (unsigned short*)alloc(32768);
    unsigned short* F1H  = (unsigned short*)alloc(16384);
    unsigned short* F1L  = (unsigned short*)alloc(16384);
    size_t base_need = off;
    if (ws_size < base_need) return;
    float2* Wt = (float2*)alloc(37748736);                    // [4][288][64][64]
    bool use_wt = (ws_size >= off);

    k_tables2<<<1, 256, 0, stream>>>(TfH, TfL, TiXH, TiXL, TDH, TDL, TIH, TIL);
    k_spec<<<1, 64, 0, stream>>>(xs, ts, Sx, St);
    k_u<<<16, 64, 0, stream>>>(u0, fc0_w, fc0_b, U);
    k_wprep<<<64, 256, 0, stream>>>(wconv, fc1w, WH, WL, F1H, F1L);
    k_cw<<<16, 64, 0, stream>>>(wconv, bconv, fc0_w, U, Ww0, Ww1, WU);
    k_hm0<<<288, 256, 0, stream>>>(fc0_w, U, Sx, St, Hm);
    if (use_wt)
        k_wt<<<512, 256, 0, stream>>>(w1re, w1im, w2re, w2im, Wt);

    for (int l = 0; l < 4; ++l) {
        if (l > 0)
            k_dftt2<<<192, 256, 0, stream>>>(A2H, A2L, TDH, TDL, Hm);
        if (use_wt)
            k_mix<<<576, 256, 0, stream>>>(Hm, Wt + (size_t)l * 288 * 4096, Om);
        else
            k_mix_raw<<<576, 256, 0, stream>>>(Hm, w1re + (size_t)l * 589824, w1im + (size_t)l * 589824,
                                               w2re + (size_t)l * 589824, w2im + (size_t)l * 589824, Om);
        k_idftt2<<<1024, 256, 0, stream>>>(Om, TIH, TIL, BvH, BvL);
        if (l == 0)
            k_conv_mid<1><<<2048, 256, 0, stream>>>(hTH, hTL, WH, WL, BvH, BvL, TiXH, TiXL,
                                                    TfH, TfL, A2H, A2L, bconv, xs, ts, Ww0, Ww1, WU);
        else if (l < 3)
            k_conv_mid<0><<<2048, 256, 0, stream>>>(hTH, hTL, WH + l * 4096, WL + l * 4096,
                                                    BvH, BvL, TiXH, TiXL, TfH, TfL, A2H, A2L,
                                                    bconv + l * 64, xs, ts, Ww0, Ww1, WU);
        else
            k_conv_head<<<2048, 256, 0, stream>>>(hTH, hTL, WH + 3 * 4096, WL + 3 * 4096,
                                                  BvH, BvL, TiXH, TiXL, bconv + 3 * 64,
                                                  F1H, F1L, fc1b, fc2w, fc2b, out);
    }
}